// Round 1
// baseline (206.028 us; speedup 1.0000x reference)
//
#include <hip/hip_runtime.h>
#include <hip/hip_bf16.h>
#include <math.h>

// Problem constants
#define BB 32
#define SS 16384
#define MM 64
#define HID 512
#define EPSV 1e-8f

// ws layout (in floats)
#define OFF_H   0            // 32*512 h vectors
#define OFF_P   16384        // 32*512 per-batch params
#define OFF_SER 32768        // 32 sum of e_r
#define OFF_SEW 32800        // 32 sum of e_w
#define OFF_SGR 32832        // 32 sum of wgam_r
#define OFF_SGW 32864        // 32 sum of wgam_w
#define OFF_R   32896        // 32*64 read vector accumulators
#define OFF_ER  40960        // 32*16384 e_r
#define OFF_EW  (OFF_ER + BB*SS)
#define OFF_WGR (OFF_EW + BB*SS)
#define OFF_WGW (OFF_WGR + BB*SS)
// total = 40960 + 4*524288 = 2,138,112 floats = 8.55 MB

__device__ __forceinline__ float sigmoidf_(float x) { return 1.f / (1.f + expf(-x)); }
__device__ __forceinline__ float softplusf_(float x) {
    return (x > 0.f) ? x + log1pf(expf(-x)) : log1pf(expf(x));
}

// Zero the atomic accumulators (ws is poisoned once and never re-poisoned).
__global__ void k_init(float* ws) {
    for (int i = threadIdx.x; i < 128 + BB * MM; i += 256) ws[OFF_SER + i] = 0.f;
}

// Per-batch: LSTM h, read/write head raw outputs -> derived params into ws.
__global__ void k_prep(const float* __restrict__ x, const float* __restrict__ pdo,
                       const float* __restrict__ prv,
                       const float* __restrict__ W_ih, const float* __restrict__ b_ih,
                       const float* __restrict__ b_hh,
                       const float* __restrict__ W_r, const float* __restrict__ b_r,
                       const float* __restrict__ W_w, const float* __restrict__ b_w,
                       float* __restrict__ ws) {
    int b = blockIdx.x, tid = threadIdx.x;
    __shared__ float xt[192];
    __shared__ float hs[512];
    __shared__ float outr[70];
    __shared__ float outw[198];
    if (tid < 64) {
        xt[tid]       = x[b * 64 + tid];
        xt[64 + tid]  = pdo[b * 64 + tid];
        xt[128 + tid] = prv[b * 64 + tid];
    }
    __syncthreads();
    for (int t = tid; t < 512; t += 256) {
        float zi = b_ih[t] + b_hh[t];
        float zg = b_ih[1024 + t] + b_hh[1024 + t];
        float zo = b_ih[1536 + t] + b_hh[1536 + t];
        const float* wi = W_ih + (size_t)t * 192;
        const float* wg = W_ih + (size_t)(1024 + t) * 192;
        const float* wo = W_ih + (size_t)(1536 + t) * 192;
        #pragma unroll 4
        for (int k = 0; k < 192; k++) {
            float xv = xt[k];
            zi = fmaf(xv, wi[k], zi);
            zg = fmaf(xv, wg[k], zg);
            zo = fmaf(xv, wo[k], zo);
        }
        float c = sigmoidf_(zi) * tanhf(zg);
        hs[t] = sigmoidf_(zo) * tanhf(c);
    }
    __syncthreads();
    for (int j = tid; j < 268; j += 256) {
        if (j < 70) {
            float acc = b_r[j];
            const float* wr = W_r + (size_t)j * 512;
            for (int t = 0; t < 512; t++) acc = fmaf(hs[t], wr[t], acc);
            outr[j] = acc;
        } else {
            int jj = j - 70;
            float acc = b_w[jj];
            const float* wwp = W_w + (size_t)jj * 512;
            for (int t = 0; t < 512; t++) acc = fmaf(hs[t], wwp[t], acc);
            outw[jj] = acc;
        }
    }
    __syncthreads();
    float* P = ws + OFF_P + (size_t)b * 512;
    for (int t = tid; t < 512; t += 256) ws[OFF_H + (size_t)b * 512 + t] = hs[t];
    if (tid < 64) {
        P[tid]       = outr[tid];        // k_r
        P[128 + tid] = outw[tid];        // k_w
        P[256 + tid] = outw[70 + tid];   // erase
        P[320 + tid] = outw[134 + tid];  // add
    }
    if (tid == 0) {
        float n2 = 0;
        for (int m = 0; m < 64; m++) n2 += outr[m] * outr[m];
        P[70] = 1.f / fmaxf(sqrtf(n2), EPSV);
        P[64] = softplusf_(outr[64]);
        P[65] = sigmoidf_(outr[65]);
        float s0 = softplusf_(outr[66]), s1 = softplusf_(outr[67]), s2 = softplusf_(outr[68]);
        float mx = fmaxf(s0, fmaxf(s1, s2));
        float e0 = expf(s0 - mx), e1 = expf(s1 - mx), e2 = expf(s2 - mx);
        float si = 1.f / (e0 + e1 + e2);
        P[66] = e0 * si; P[67] = e1 * si; P[68] = e2 * si;
        P[69] = 1.f + softplusf_(outr[69]);
    }
    if (tid == 1) {
        float n2 = 0;
        for (int m = 0; m < 64; m++) n2 += outw[m] * outw[m];
        P[198] = 1.f / fmaxf(sqrtf(n2), EPSV);
        P[192] = softplusf_(outw[64]);
        P[193] = sigmoidf_(outw[65]);
        float s0 = softplusf_(outw[66]), s1 = softplusf_(outw[67]), s2 = softplusf_(outw[68]);
        float mx = fmaxf(s0, fmaxf(s1, s2));
        float e0 = expf(s0 - mx), e1 = expf(s1 - mx), e2 = expf(s2 - mx);
        float si = 1.f / (e0 + e1 + e2);
        P[194] = e0 * si; P[195] = e1 * si; P[196] = e2 * si;
        P[197] = 1.f + softplusf_(outw[69]);
    }
}

// Pass over memory: e_r/e_w = exp(beta*(cos-1)) (stable shift, cos<=1), per-batch sums.
__global__ void k_scores(const float* __restrict__ mem, float* __restrict__ ws) {
    int b = blockIdx.x >> 6;
    int chunk = blockIdx.x & 63;
    int tid = threadIdx.x;
    int rowslot = tid >> 4, col = tid & 15;
    const float* P = ws + OFF_P + (size_t)b * 512;
    float4 kr = *(const float4*)(P + col * 4);
    float4 kw = *(const float4*)(P + 128 + col * 4);
    float beta_r = P[64], ikr = P[70], beta_w = P[192], ikw = P[198];
    float* e_r = ws + OFF_ER + (size_t)b * SS;
    float* e_w = ws + OFF_EW + (size_t)b * SS;
    float se_r = 0.f, se_w = 0.f;
    int row0 = chunk * 256;
    for (int it = 0; it < 16; ++it) {
        int row = row0 + it * 16 + rowslot;
        float4 v = *(const float4*)(mem + ((size_t)b * SS + row) * 64 + col * 4);
        float dr = v.x * kr.x + v.y * kr.y + v.z * kr.z + v.w * kr.w;
        float dw = v.x * kw.x + v.y * kw.y + v.z * kw.z + v.w * kw.w;
        float n2 = v.x * v.x + v.y * v.y + v.z * v.z + v.w * v.w;
        #pragma unroll
        for (int off = 8; off >= 1; off >>= 1) {
            dr += __shfl_xor(dr, off);
            dw += __shfl_xor(dw, off);
            n2 += __shfl_xor(n2, off);
        }
        float imn = 1.f / fmaxf(sqrtf(n2), EPSV);
        float er = expf(beta_r * (dr * ikr * imn - 1.f));
        float ew = expf(beta_w * (dw * ikw * imn - 1.f));
        if (col == 0) {
            e_r[row] = er;
            e_w[row] = ew;
            se_r += er;
            se_w += ew;
        }
    }
    __shared__ float red[2];
    if (tid == 0) { red[0] = 0.f; red[1] = 0.f; }
    __syncthreads();
    if (col == 0) { atomicAdd(&red[0], se_r); atomicAdd(&red[1], se_w); }
    __syncthreads();
    if (tid == 0) {
        atomicAdd(ws + OFF_SER + b, red[0]);
        atomicAdd(ws + OFF_SEW + b, red[1]);
    }
}

// wg -> shift-convolve -> ^gamma, write wgam arrays + per-batch sums.
__global__ void k_wgam(float* __restrict__ ws) {
    int i = blockIdx.x * 256 + threadIdx.x;   // 0 .. 32*16384-1, each block within one b
    int b = i >> 14, s = i & (SS - 1);
    const float* P = ws + OFF_P + (size_t)b * 512;
    const float* e_r = ws + OFF_ER + (size_t)b * SS;
    const float* e_w = ws + OFF_EW + (size_t)b * SS;
    float inv_ser = 1.f / ws[OFF_SER + b];
    float inv_sew = 1.f / ws[OFF_SEW + b];
    int sm = (s == 0) ? (SS - 1) : (s - 1);
    int sp = (s == SS - 1) ? 0 : (s + 1);
    float wsr = P[65] * inv_ser * (P[66] * e_r[sm] + P[67] * e_r[s] + P[68] * e_r[sp]);
    float wgr = powf(wsr, P[69]);
    float wsw = P[193] * inv_sew * (P[194] * e_w[sm] + P[195] * e_w[s] + P[196] * e_w[sp]);
    float wgw = powf(wsw, P[197]);
    ws[OFF_WGR + (size_t)b * SS + s] = wgr;
    ws[OFF_WGW + (size_t)b * SS + s] = wgw;
    float rr = wgr, rw = wgw;
    #pragma unroll
    for (int off = 32; off >= 1; off >>= 1) {
        rr += __shfl_xor(rr, off);
        rw += __shfl_xor(rw, off);
    }
    __shared__ float lr[4], lw[4];
    int wv = threadIdx.x >> 6, ln = threadIdx.x & 63;
    if (ln == 0) { lr[wv] = rr; lw[wv] = rw; }
    __syncthreads();
    if (threadIdx.x == 0) {
        atomicAdd(ws + OFF_SGR + b, lr[0] + lr[1] + lr[2] + lr[3]);
        atomicAdd(ws + OFF_SGW + b, lw[0] + lw[1] + lw[2] + lw[3]);
    }
}

// Final weights; r = sum_s w_r*mem; new_mem = mem*(1-w_w*e)+w_w*a.
__global__ void k_update(const float* __restrict__ mem, float* __restrict__ ws,
                         float* __restrict__ out) {
    int b = blockIdx.x >> 6, chunk = blockIdx.x & 63, tid = threadIdx.x;
    int rowslot = tid >> 4, col = tid & 15;
    const float* P = ws + OFF_P + (size_t)b * 512;
    float4 er4 = *(const float4*)(P + 256 + col * 4);
    float4 ad4 = *(const float4*)(P + 320 + col * 4);
    float isr = 1.f / ws[OFF_SGR + b];
    float isw = 1.f / ws[OFF_SGW + b];
    const float* wgr = ws + OFF_WGR + (size_t)b * SS;
    const float* wgw = ws + OFF_WGW + (size_t)b * SS;
    float* nm = out + 2048 + (size_t)b * SS * 64;
    float4 racc = {0.f, 0.f, 0.f, 0.f};
    int row0 = chunk * 256;
    for (int it = 0; it < 16; ++it) {
        int row = row0 + it * 16 + rowslot;
        float wr = wgr[row] * isr;
        float ww = wgw[row] * isw;
        float4 v = *(const float4*)(mem + ((size_t)b * SS + row) * 64 + col * 4);
        racc.x = fmaf(wr, v.x, racc.x);
        racc.y = fmaf(wr, v.y, racc.y);
        racc.z = fmaf(wr, v.z, racc.z);
        racc.w = fmaf(wr, v.w, racc.w);
        float4 o4;
        o4.x = v.x * (1.f - ww * er4.x) + ww * ad4.x;
        o4.y = v.y * (1.f - ww * er4.y) + ww * ad4.y;
        o4.z = v.z * (1.f - ww * er4.z) + ww * ad4.z;
        o4.w = v.w * (1.f - ww * er4.w) + ww * ad4.w;
        *(float4*)(nm + (size_t)row * 64 + col * 4) = o4;
    }
    __shared__ float4 red[256];
    red[tid] = racc;
    __syncthreads();
    if (tid < 16) {
        float4 a = red[tid];
        for (int rs = 1; rs < 16; ++rs) {
            float4 t2 = red[rs * 16 + tid];
            a.x += t2.x; a.y += t2.y; a.z += t2.z; a.w += t2.w;
        }
        atomicAdd(ws + OFF_R + b * 64 + tid * 4 + 0, a.x);
        atomicAdd(ws + OFF_R + b * 64 + tid * 4 + 1, a.y);
        atomicAdd(ws + OFF_R + b * 64 + tid * 4 + 2, a.z);
        atomicAdd(ws + OFF_R + b * 64 + tid * 4 + 3, a.w);
    }
}

// output = softmax(concat(h, r) @ W_o.T + b_o); one wave per batch.
__global__ void k_out(const float* __restrict__ ws, const float* __restrict__ W_o,
                      const float* __restrict__ b_o, float* __restrict__ out) {
    int b = blockIdx.x, o = threadIdx.x;  // 64 threads
    const float* h = ws + OFF_H + (size_t)b * 512;
    const float* r = ws + OFF_R + (size_t)b * 64;
    const float* w = W_o + (size_t)o * 576;
    float acc = b_o[o];
    for (int t = 0; t < 512; t++) acc = fmaf(h[t], w[t], acc);
    for (int m = 0; m < 64; m++) acc = fmaf(r[m], w[512 + m], acc);
    float mx = acc;
    #pragma unroll
    for (int off = 32; off >= 1; off >>= 1) mx = fmaxf(mx, __shfl_xor(mx, off));
    float e = expf(acc - mx);
    float sm = e;
    #pragma unroll
    for (int off = 32; off >= 1; off >>= 1) sm += __shfl_xor(sm, off);
    out[b * 64 + o] = e / sm;
}

extern "C" void kernel_launch(void* const* d_in, const int* in_sizes, int n_in,
                              void* d_out, int out_size, void* d_ws, size_t ws_size,
                              hipStream_t stream) {
    const float* x    = (const float*)d_in[0];
    const float* pdo  = (const float*)d_in[1];
    const float* prv  = (const float*)d_in[2];
    const float* mem  = (const float*)d_in[3];
    const float* W_ih = (const float*)d_in[4];
    // d_in[5] = W_hh (unused by reference math)
    const float* b_ih = (const float*)d_in[6];
    const float* b_hh = (const float*)d_in[7];
    const float* W_r  = (const float*)d_in[8];
    const float* b_r  = (const float*)d_in[9];
    const float* W_w  = (const float*)d_in[10];
    const float* b_w  = (const float*)d_in[11];
    const float* W_o  = (const float*)d_in[12];
    const float* b_o  = (const float*)d_in[13];
    float* out = (float*)d_out;
    float* ws  = (float*)d_ws;

    k_init<<<1, 256, 0, stream>>>(ws);
    k_prep<<<BB, 256, 0, stream>>>(x, pdo, prv, W_ih, b_ih, b_hh, W_r, b_r, W_w, b_w, ws);
    k_scores<<<BB * 64, 256, 0, stream>>>(mem, ws);
    k_wgam<<<BB * 64, 256, 0, stream>>>(ws);
    k_update<<<BB * 64, 256, 0, stream>>>(mem, ws, out);
    k_out<<<BB, 64, 0, stream>>>(ws, W_o, b_o, out);
}

// Round 2
// 154.441 us; speedup vs baseline: 1.3340x; 1.3340x over previous
//
#include <hip/hip_runtime.h>
#include <hip/hip_bf16.h>
#include <math.h>

// Problem constants
#define BB 32
#define SS 16384
#define MM 64
#define HID 512
#define EPSV 1e-8f

// ws layout (in floats)
#define OFF_H   0            // 32*512 h vectors
#define OFF_P   16384        // 32*512 per-batch params (sparse layout, see below)
#define OFF_SER 32768        // 32 sum of e_r
#define OFF_SEW 32800        // 32 sum of e_w
#define OFF_SGR 32832        // 32 sum of wgam_r
#define OFF_SGW 32864        // 32 sum of wgam_w
#define OFF_R   32896        // 32*64 read vector accumulators
#define OFF_ER  40960        // 32*16384 e_r
#define OFF_EW  (OFF_ER + BB*SS)
#define OFF_WGR (OFF_EW + BB*SS)
#define OFF_WGW (OFF_WGR + BB*SS)
// total = 40960 + 4*524288 = 2,138,112 floats = 8.55 MB
//
// P-region per-batch layout (512 floats):
//  [0..63]   k_r            [64] beta_r  [65] g_r  [66..68] shift_r  [69] gamma_r
//  [70]      1/||k_r||      [96..98] raw shift_r (pre-softplus)
//  [128..191] k_w           [192] beta_w [193] g_w [194..196] shift_w [197] gamma_w
//  [198]     1/||k_w||      [224..226] raw shift_w
//  [256..319] erase         [320..383] add

__device__ __forceinline__ float sigmoidf_(float x) { return 1.f / (1.f + expf(-x)); }
__device__ __forceinline__ float softplusf_(float x) {
    return (x > 0.f) ? x + log1pf(expf(-x)) : log1pf(expf(x));
}

// Zero the atomic accumulators (ws is poisoned once and never re-poisoned).
__global__ void k_init(float* ws) {
    for (int i = threadIdx.x; i < 128 + BB * MM; i += 256) ws[OFF_SER + i] = 0.f;
}

// One wave per (b,t): h[b][t]. Lanes split the 192-long dot, coalesced W reads.
__global__ void k_lstm(const float* __restrict__ x, const float* __restrict__ pdo,
                       const float* __restrict__ prv,
                       const float* __restrict__ W_ih, const float* __restrict__ b_ih,
                       const float* __restrict__ b_hh, float* __restrict__ ws) {
    int wid = blockIdx.x * 4 + (threadIdx.x >> 6);   // 0 .. 32*512-1
    int lane = threadIdx.x & 63;
    int b = wid >> 9, t = wid & 511;
    float x0 = x[b * 64 + lane];
    float x1 = pdo[b * 64 + lane];
    float x2 = prv[b * 64 + lane];
    const float* wi = W_ih + (size_t)t * 192;
    const float* wg = W_ih + (size_t)(1024 + t) * 192;
    const float* wo = W_ih + (size_t)(1536 + t) * 192;
    float zi = x0 * wi[lane] + x1 * wi[64 + lane] + x2 * wi[128 + lane];
    float zg = x0 * wg[lane] + x1 * wg[64 + lane] + x2 * wg[128 + lane];
    float zo = x0 * wo[lane] + x1 * wo[64 + lane] + x2 * wo[128 + lane];
    #pragma unroll
    for (int off = 32; off >= 1; off >>= 1) {
        zi += __shfl_xor(zi, off);
        zg += __shfl_xor(zg, off);
        zo += __shfl_xor(zo, off);
    }
    if (lane == 0) {
        zi += b_ih[t] + b_hh[t];
        zg += b_ih[1024 + t] + b_hh[1024 + t];
        zo += b_ih[1536 + t] + b_hh[1536 + t];
        float c = sigmoidf_(zi) * tanhf(zg);
        ws[OFF_H + (size_t)b * 512 + t] = sigmoidf_(zo) * tanhf(c);
    }
}

// One wave per (b, head-row j): j<70 read head, else write head row j-70.
__global__ void k_heads(const float* __restrict__ W_r, const float* __restrict__ b_r,
                        const float* __restrict__ W_w, const float* __restrict__ b_w,
                        float* __restrict__ ws) {
    int wid = blockIdx.x * 4 + (threadIdx.x >> 6);   // 0 .. 32*268-1
    int lane = threadIdx.x & 63;
    int b = wid / 268, j = wid % 268;
    const float* h = ws + OFF_H + (size_t)b * 512;
    const float* wrow;
    float bias;
    if (j < 70) { wrow = W_r + (size_t)j * 512; bias = b_r[j]; }
    else        { wrow = W_w + (size_t)(j - 70) * 512; bias = b_w[j - 70]; }
    float acc = 0.f;
    #pragma unroll
    for (int c = 0; c < 8; c++) acc = fmaf(h[c * 64 + lane], wrow[c * 64 + lane], acc);
    #pragma unroll
    for (int off = 32; off >= 1; off >>= 1) acc += __shfl_xor(acc, off);
    if (lane != 0) return;
    acc += bias;
    float* P = ws + OFF_P + (size_t)b * 512;
    if (j < 70) {
        if (j < 64)       P[j] = acc;                       // k_r
        else if (j == 64) P[64] = softplusf_(acc);          // beta_r
        else if (j == 65) P[65] = sigmoidf_(acc);           // g_r
        else if (j <= 68) P[96 + (j - 66)] = acc;           // raw shift_r
        else              P[69] = 1.f + softplusf_(acc);    // gamma_r
    } else {
        int jj = j - 70;
        if (jj < 64)       P[128 + jj] = acc;               // k_w
        else if (jj == 64) P[192] = softplusf_(acc);        // beta_w
        else if (jj == 65) P[193] = sigmoidf_(acc);         // g_w
        else if (jj <= 68) P[224 + (jj - 66)] = acc;        // raw shift_w
        else if (jj == 69) P[197] = 1.f + softplusf_(acc);  // gamma_w
        else if (jj < 134) P[256 + (jj - 70)] = acc;        // erase
        else               P[320 + (jj - 134)] = acc;       // add
    }
}

// Finish coupled params: key norms + shift 3-softmax. One wave per batch.
__global__ void k_params(float* __restrict__ ws) {
    int b = blockIdx.x, lane = threadIdx.x;
    float* P = ws + OFF_P + (size_t)b * 512;
    float kr = P[lane], kw = P[128 + lane];
    float nr = kr * kr, nw = kw * kw;
    #pragma unroll
    for (int off = 32; off >= 1; off >>= 1) {
        nr += __shfl_xor(nr, off);
        nw += __shfl_xor(nw, off);
    }
    if (lane == 0) {
        P[70]  = 1.f / fmaxf(sqrtf(nr), EPSV);
        P[198] = 1.f / fmaxf(sqrtf(nw), EPSV);
        float s0 = softplusf_(P[96]), s1 = softplusf_(P[97]), s2 = softplusf_(P[98]);
        float mx = fmaxf(s0, fmaxf(s1, s2));
        float e0 = expf(s0 - mx), e1 = expf(s1 - mx), e2 = expf(s2 - mx);
        float si = 1.f / (e0 + e1 + e2);
        P[66] = e0 * si; P[67] = e1 * si; P[68] = e2 * si;
        s0 = softplusf_(P[224]); s1 = softplusf_(P[225]); s2 = softplusf_(P[226]);
        mx = fmaxf(s0, fmaxf(s1, s2));
        e0 = expf(s0 - mx); e1 = expf(s1 - mx); e2 = expf(s2 - mx);
        si = 1.f / (e0 + e1 + e2);
        P[194] = e0 * si; P[195] = e1 * si; P[196] = e2 * si;
    }
}

// Pass over memory: e_r/e_w = exp(beta*(cos-1)) (stable shift, cos<=1), per-batch sums.
__global__ void k_scores(const float* __restrict__ mem, float* __restrict__ ws) {
    int b = blockIdx.x >> 6;
    int chunk = blockIdx.x & 63;
    int tid = threadIdx.x;
    int rowslot = tid >> 4, col = tid & 15;
    const float* P = ws + OFF_P + (size_t)b * 512;
    float4 kr = *(const float4*)(P + col * 4);
    float4 kw = *(const float4*)(P + 128 + col * 4);
    float beta_r = P[64], ikr = P[70], beta_w = P[192], ikw = P[198];
    float* e_r = ws + OFF_ER + (size_t)b * SS;
    float* e_w = ws + OFF_EW + (size_t)b * SS;
    float se_r = 0.f, se_w = 0.f;
    int row0 = chunk * 256;
    for (int it = 0; it < 16; ++it) {
        int row = row0 + it * 16 + rowslot;
        float4 v = *(const float4*)(mem + ((size_t)b * SS + row) * 64 + col * 4);
        float dr = v.x * kr.x + v.y * kr.y + v.z * kr.z + v.w * kr.w;
        float dw = v.x * kw.x + v.y * kw.y + v.z * kw.z + v.w * kw.w;
        float n2 = v.x * v.x + v.y * v.y + v.z * v.z + v.w * v.w;
        #pragma unroll
        for (int off = 8; off >= 1; off >>= 1) {
            dr += __shfl_xor(dr, off);
            dw += __shfl_xor(dw, off);
            n2 += __shfl_xor(n2, off);
        }
        float imn = 1.f / fmaxf(sqrtf(n2), EPSV);
        float er = expf(beta_r * (dr * ikr * imn - 1.f));
        float ew = expf(beta_w * (dw * ikw * imn - 1.f));
        if (col == 0) {
            e_r[row] = er;
            e_w[row] = ew;
            se_r += er;
            se_w += ew;
        }
    }
    __shared__ float red[2];
    if (tid == 0) { red[0] = 0.f; red[1] = 0.f; }
    __syncthreads();
    if (col == 0) { atomicAdd(&red[0], se_r); atomicAdd(&red[1], se_w); }
    __syncthreads();
    if (tid == 0) {
        atomicAdd(ws + OFF_SER + b, red[0]);
        atomicAdd(ws + OFF_SEW + b, red[1]);
    }
}

// wg -> shift-convolve -> ^gamma, write wgam arrays + per-batch sums.
__global__ void k_wgam(float* __restrict__ ws) {
    int i = blockIdx.x * 256 + threadIdx.x;   // each block within one b
    int b = i >> 14, s = i & (SS - 1);
    const float* P = ws + OFF_P + (size_t)b * 512;
    const float* e_r = ws + OFF_ER + (size_t)b * SS;
    const float* e_w = ws + OFF_EW + (size_t)b * SS;
    float inv_ser = 1.f / ws[OFF_SER + b];
    float inv_sew = 1.f / ws[OFF_SEW + b];
    int sm = (s == 0) ? (SS - 1) : (s - 1);
    int sp = (s == SS - 1) ? 0 : (s + 1);
    float wsr = P[65] * inv_ser * (P[66] * e_r[sm] + P[67] * e_r[s] + P[68] * e_r[sp]);
    float wgr = powf(wsr, P[69]);
    float wsw = P[193] * inv_sew * (P[194] * e_w[sm] + P[195] * e_w[s] + P[196] * e_w[sp]);
    float wgw = powf(wsw, P[197]);
    ws[OFF_WGR + (size_t)b * SS + s] = wgr;
    ws[OFF_WGW + (size_t)b * SS + s] = wgw;
    float rr = wgr, rw = wgw;
    #pragma unroll
    for (int off = 32; off >= 1; off >>= 1) {
        rr += __shfl_xor(rr, off);
        rw += __shfl_xor(rw, off);
    }
    __shared__ float lr[4], lw[4];
    int wv = threadIdx.x >> 6, ln = threadIdx.x & 63;
    if (ln == 0) { lr[wv] = rr; lw[wv] = rw; }
    __syncthreads();
    if (threadIdx.x == 0) {
        atomicAdd(ws + OFF_SGR + b, lr[0] + lr[1] + lr[2] + lr[3]);
        atomicAdd(ws + OFF_SGW + b, lw[0] + lw[1] + lw[2] + lw[3]);
    }
}

// Final weights; r = sum_s w_r*mem; new_mem = mem*(1-w_w*e)+w_w*a.
__global__ void k_update(const float* __restrict__ mem, float* __restrict__ ws,
                         float* __restrict__ out) {
    int b = blockIdx.x >> 6, chunk = blockIdx.x & 63, tid = threadIdx.x;
    int rowslot = tid >> 4, col = tid & 15;
    const float* P = ws + OFF_P + (size_t)b * 512;
    float4 er4 = *(const float4*)(P + 256 + col * 4);
    float4 ad4 = *(const float4*)(P + 320 + col * 4);
    float isr = 1.f / ws[OFF_SGR + b];
    float isw = 1.f / ws[OFF_SGW + b];
    const float* wgr = ws + OFF_WGR + (size_t)b * SS;
    const float* wgw = ws + OFF_WGW + (size_t)b * SS;
    float* nm = out + 2048 + (size_t)b * SS * 64;
    float4 racc = {0.f, 0.f, 0.f, 0.f};
    int row0 = chunk * 256;
    for (int it = 0; it < 16; ++it) {
        int row = row0 + it * 16 + rowslot;
        float wr = wgr[row] * isr;
        float ww = wgw[row] * isw;
        float4 v = *(const float4*)(mem + ((size_t)b * SS + row) * 64 + col * 4);
        racc.x = fmaf(wr, v.x, racc.x);
        racc.y = fmaf(wr, v.y, racc.y);
        racc.z = fmaf(wr, v.z, racc.z);
        racc.w = fmaf(wr, v.w, racc.w);
        float4 o4;
        o4.x = v.x * (1.f - ww * er4.x) + ww * ad4.x;
        o4.y = v.y * (1.f - ww * er4.y) + ww * ad4.y;
        o4.z = v.z * (1.f - ww * er4.z) + ww * ad4.z;
        o4.w = v.w * (1.f - ww * er4.w) + ww * ad4.w;
        *(float4*)(nm + (size_t)row * 64 + col * 4) = o4;
    }
    __shared__ float4 red[256];
    red[tid] = racc;
    __syncthreads();
    if (tid < 16) {
        float4 a = red[tid];
        for (int rs = 1; rs < 16; ++rs) {
            float4 t2 = red[rs * 16 + tid];
            a.x += t2.x; a.y += t2.y; a.z += t2.z; a.w += t2.w;
        }
        atomicAdd(ws + OFF_R + b * 64 + tid * 4 + 0, a.x);
        atomicAdd(ws + OFF_R + b * 64 + tid * 4 + 1, a.y);
        atomicAdd(ws + OFF_R + b * 64 + tid * 4 + 2, a.z);
        atomicAdd(ws + OFF_R + b * 64 + tid * 4 + 3, a.w);
    }
}

// output = softmax(concat(h, r) @ W_o.T + b_o); one wave per batch.
__global__ void k_out(const float* __restrict__ ws, const float* __restrict__ W_o,
                      const float* __restrict__ b_o, float* __restrict__ out) {
    int b = blockIdx.x, o = threadIdx.x;  // 64 threads
    const float* h = ws + OFF_H + (size_t)b * 512;
    const float* r = ws + OFF_R + (size_t)b * 64;
    const float* w = W_o + (size_t)o * 576;
    float acc = b_o[o];
    for (int t = 0; t < 512; t++) acc = fmaf(h[t], w[t], acc);
    for (int m = 0; m < 64; m++) acc = fmaf(r[m], w[512 + m], acc);
    float mx = acc;
    #pragma unroll
    for (int off = 32; off >= 1; off >>= 1) mx = fmaxf(mx, __shfl_xor(mx, off));
    float e = expf(acc - mx);
    float sm = e;
    #pragma unroll
    for (int off = 32; off >= 1; off >>= 1) sm += __shfl_xor(sm, off);
    out[b * 64 + o] = e / sm;
}

extern "C" void kernel_launch(void* const* d_in, const int* in_sizes, int n_in,
                              void* d_out, int out_size, void* d_ws, size_t ws_size,
                              hipStream_t stream) {
    const float* x    = (const float*)d_in[0];
    const float* pdo  = (const float*)d_in[1];
    const float* prv  = (const float*)d_in[2];
    const float* mem  = (const float*)d_in[3];
    const float* W_ih = (const float*)d_in[4];
    // d_in[5] = W_hh (unused by reference math)
    const float* b_ih = (const float*)d_in[6];
    const float* b_hh = (const float*)d_in[7];
    const float* W_r  = (const float*)d_in[8];
    const float* b_r  = (const float*)d_in[9];
    const float* W_w  = (const float*)d_in[10];
    const float* b_w  = (const float*)d_in[11];
    const float* W_o  = (const float*)d_in[12];
    const float* b_o  = (const float*)d_in[13];
    float* out = (float*)d_out;
    float* ws  = (float*)d_ws;

    k_init<<<1, 256, 0, stream>>>(ws);
    k_lstm<<<BB * 512 / 4, 256, 0, stream>>>(x, pdo, prv, W_ih, b_ih, b_hh, ws);
    k_heads<<<(BB * 268) / 4, 256, 0, stream>>>(W_r, b_r, W_w, b_w, ws);
    k_params<<<BB, 64, 0, stream>>>(ws);
    k_scores<<<BB * 64, 256, 0, stream>>>(mem, ws);
    k_wgam<<<BB * 64, 256, 0, stream>>>(ws);
    k_update<<<BB * 64, 256, 0, stream>>>(mem, ws, out);
    k_out<<<BB, 64, 0, stream>>>(ws, W_o, b_o, out);
}

// Round 3
// 121.550 us; speedup vs baseline: 1.6950x; 1.2706x over previous
//
#include <hip/hip_runtime.h>
#include <hip/hip_bf16.h>
#include <math.h>

// Problem constants
#define BB 32
#define SS 16384
#define MM 64
#define HID 512
#define EPSV 1e-8f

// ws layout (in floats)
#define OFF_H   0            // 32*512 h vectors
#define OFF_P   16384        // 32*512 per-batch params (sparse layout, see below)
#define OFF_SER 32768        // (unused now, still zeroed)
#define OFF_SEW 32800
#define OFF_SGR 32832        // 32 sum of wgam_r
#define OFF_SGW 32864        // 32 sum of wgam_w
#define OFF_R   32896        // 32*64 read vector accumulators
#define OFF_ER  40960        // (unused now)
#define OFF_EW  (OFF_ER + BB*SS)
#define OFF_WGR (OFF_EW + BB*SS)
#define OFF_WGW (OFF_WGR + BB*SS)
//
// P-region per-batch layout (512 floats):
//  [0..63]   k_r            [64] beta_r  [65] g_r (unused)  [69] gamma_r
//  [96..98]  raw shift_r (pre-softplus)
//  [128..191] k_w           [192] beta_w [193] g_w (unused) [197] gamma_w
//  [224..226] raw shift_w
//  [256..319] erase         [320..383] add

__device__ __forceinline__ float sigmoidf_(float x) { return 1.f / (1.f + expf(-x)); }
__device__ __forceinline__ float softplusf_(float x) {
    return (x > 0.f) ? x + log1pf(expf(-x)) : log1pf(expf(x));
}

// One wave per (b,t): h[b][t]. Block 0 also zeroes the atomic accumulators.
__global__ void k_lstm(const float* __restrict__ x, const float* __restrict__ pdo,
                       const float* __restrict__ prv,
                       const float* __restrict__ W_ih, const float* __restrict__ b_ih,
                       const float* __restrict__ b_hh, float* __restrict__ ws) {
    if (blockIdx.x == 0) {
        for (int i = threadIdx.x; i < 128 + BB * MM; i += 256) ws[OFF_SER + i] = 0.f;
    }
    int wid = blockIdx.x * 4 + (threadIdx.x >> 6);   // 0 .. 32*512-1
    int lane = threadIdx.x & 63;
    int b = wid >> 9, t = wid & 511;
    float x0 = x[b * 64 + lane];
    float x1 = pdo[b * 64 + lane];
    float x2 = prv[b * 64 + lane];
    const float* wi = W_ih + (size_t)t * 192;
    const float* wg = W_ih + (size_t)(1024 + t) * 192;
    const float* wo = W_ih + (size_t)(1536 + t) * 192;
    float zi = x0 * wi[lane] + x1 * wi[64 + lane] + x2 * wi[128 + lane];
    float zg = x0 * wg[lane] + x1 * wg[64 + lane] + x2 * wg[128 + lane];
    float zo = x0 * wo[lane] + x1 * wo[64 + lane] + x2 * wo[128 + lane];
    #pragma unroll
    for (int off = 32; off >= 1; off >>= 1) {
        zi += __shfl_xor(zi, off);
        zg += __shfl_xor(zg, off);
        zo += __shfl_xor(zo, off);
    }
    if (lane == 0) {
        zi += b_ih[t] + b_hh[t];
        zg += b_ih[1024 + t] + b_hh[1024 + t];
        zo += b_ih[1536 + t] + b_hh[1536 + t];
        float c = sigmoidf_(zi) * tanhf(zg);
        ws[OFF_H + (size_t)b * 512 + t] = sigmoidf_(zo) * tanhf(c);
    }
}

// One wave per (b, head-row j): j<70 read head, else write head row j-70.
__global__ void k_heads(const float* __restrict__ W_r, const float* __restrict__ b_r,
                        const float* __restrict__ W_w, const float* __restrict__ b_w,
                        float* __restrict__ ws) {
    int wid = blockIdx.x * 4 + (threadIdx.x >> 6);   // 0 .. 32*268-1
    int lane = threadIdx.x & 63;
    int b = wid / 268, j = wid % 268;
    const float* h = ws + OFF_H + (size_t)b * 512;
    const float* wrow;
    float bias;
    if (j < 70) { wrow = W_r + (size_t)j * 512; bias = b_r[j]; }
    else        { wrow = W_w + (size_t)(j - 70) * 512; bias = b_w[j - 70]; }
    float acc = 0.f;
    #pragma unroll
    for (int c = 0; c < 8; c++) acc = fmaf(h[c * 64 + lane], wrow[c * 64 + lane], acc);
    #pragma unroll
    for (int off = 32; off >= 1; off >>= 1) acc += __shfl_xor(acc, off);
    if (lane != 0) return;
    acc += bias;
    float* P = ws + OFF_P + (size_t)b * 512;
    if (j < 70) {
        if (j < 64)       P[j] = acc;                       // k_r
        else if (j == 64) P[64] = softplusf_(acc);          // beta_r
        else if (j == 65) P[65] = sigmoidf_(acc);           // g_r (unused)
        else if (j <= 68) P[96 + (j - 66)] = acc;           // raw shift_r
        else              P[69] = 1.f + softplusf_(acc);    // gamma_r
    } else {
        int jj = j - 70;
        if (jj < 64)       P[128 + jj] = acc;               // k_w
        else if (jj == 64) P[192] = softplusf_(acc);        // beta_w
        else if (jj == 65) P[193] = sigmoidf_(acc);         // g_w (unused)
        else if (jj <= 68) P[224 + (jj - 66)] = acc;        // raw shift_w
        else if (jj == 69) P[197] = 1.f + softplusf_(acc);  // gamma_w
        else if (jj < 134) P[256 + (jj - 70)] = acc;        // erase
        else               P[320 + (jj - 134)] = acc;       // add
    }
}

// Fused pass over memory: E = exp(beta*(cos-1)) for this block's 256 rows plus
// the 2 circular boundary rows (kept in LDS), then shift-conv + ^gamma,
// writing wgam arrays + atomic per-batch sums. (softmax denom & gate g cancel
// in the final normalization -> no sum_e reduction needed.)
__global__ void k_scorewgam(const float* __restrict__ mem, float* __restrict__ ws) {
    int b = blockIdx.x >> 6;
    int chunk = blockIdx.x & 63;
    int tid = threadIdx.x;
    int rowslot = tid >> 4, col = tid & 15;
    const float* P = ws + OFF_P + (size_t)b * 512;

    __shared__ float sh_er[260], sh_ew[260];
    __shared__ float par[8];   // ikr, ikw, sr0..2, sw0..2

    // prologue: key norms (wave 0) + shift softmaxes (tid 0)
    if (tid < 64) {
        float kr = P[tid], kw = P[128 + tid];
        float nr = kr * kr, nw = kw * kw;
        #pragma unroll
        for (int off = 32; off >= 1; off >>= 1) {
            nr += __shfl_xor(nr, off);
            nw += __shfl_xor(nw, off);
        }
        if (tid == 0) {
            par[0] = 1.f / fmaxf(sqrtf(nr), EPSV);
            par[1] = 1.f / fmaxf(sqrtf(nw), EPSV);
            float s0 = softplusf_(P[96]), s1 = softplusf_(P[97]), s2 = softplusf_(P[98]);
            float mx = fmaxf(s0, fmaxf(s1, s2));
            float e0 = expf(s0 - mx), e1 = expf(s1 - mx), e2 = expf(s2 - mx);
            float si = 1.f / (e0 + e1 + e2);
            par[2] = e0 * si; par[3] = e1 * si; par[4] = e2 * si;
            s0 = softplusf_(P[224]); s1 = softplusf_(P[225]); s2 = softplusf_(P[226]);
            mx = fmaxf(s0, fmaxf(s1, s2));
            e0 = expf(s0 - mx); e1 = expf(s1 - mx); e2 = expf(s2 - mx);
            si = 1.f / (e0 + e1 + e2);
            par[5] = e0 * si; par[6] = e1 * si; par[7] = e2 * si;
        }
    }
    float4 kr = *(const float4*)(P + col * 4);
    float4 kw = *(const float4*)(P + 128 + col * 4);
    float beta_r = P[64], beta_w = P[192];
    float gamma_r = P[69], gamma_w = P[197];
    __syncthreads();
    float ikr = par[0], ikw = par[1];

    int row0 = chunk * 256;
    for (int it = 0; it < 17; ++it) {
        int rl = it * 16 + rowslot;             // 0..271, rows row0-1 .. row0+256
        if (rl < 258) {
            int row = (row0 - 1 + rl) & (SS - 1);
            float4 v = *(const float4*)(mem + ((size_t)b * SS + row) * 64 + col * 4);
            float dr = v.x * kr.x + v.y * kr.y + v.z * kr.z + v.w * kr.w;
            float dw = v.x * kw.x + v.y * kw.y + v.z * kw.z + v.w * kw.w;
            float n2 = v.x * v.x + v.y * v.y + v.z * v.z + v.w * v.w;
            #pragma unroll
            for (int off = 8; off >= 1; off >>= 1) {
                dr += __shfl_xor(dr, off);
                dw += __shfl_xor(dw, off);
                n2 += __shfl_xor(n2, off);
            }
            float imn = 1.f / fmaxf(sqrtf(n2), EPSV);
            if (col == 0) {
                sh_er[rl] = expf(beta_r * (dr * ikr * imn - 1.f));
                sh_ew[rl] = expf(beta_w * (dw * ikw * imn - 1.f));
            }
        }
    }
    __syncthreads();

    // conv + sharpen for row s = row0 + tid
    float wgr = powf(par[2] * sh_er[tid] + par[3] * sh_er[tid + 1] + par[4] * sh_er[tid + 2],
                     gamma_r);
    float wgw = powf(par[5] * sh_ew[tid] + par[6] * sh_ew[tid + 1] + par[7] * sh_ew[tid + 2],
                     gamma_w);
    ws[OFF_WGR + (size_t)b * SS + row0 + tid] = wgr;
    ws[OFF_WGW + (size_t)b * SS + row0 + tid] = wgw;

    float rr = wgr, rw = wgw;
    #pragma unroll
    for (int off = 32; off >= 1; off >>= 1) {
        rr += __shfl_xor(rr, off);
        rw += __shfl_xor(rw, off);
    }
    __shared__ float lr[4], lw[4];
    int wv = tid >> 6, ln = tid & 63;
    if (ln == 0) { lr[wv] = rr; lw[wv] = rw; }
    __syncthreads();
    if (tid == 0) {
        atomicAdd(ws + OFF_SGR + b, lr[0] + lr[1] + lr[2] + lr[3]);
        atomicAdd(ws + OFF_SGW + b, lw[0] + lw[1] + lw[2] + lw[3]);
    }
}

// Final weights; r = sum_s w_r*mem; new_mem = mem*(1-w_w*e)+w_w*a.
__global__ void k_update(const float* __restrict__ mem, float* __restrict__ ws,
                         float* __restrict__ out) {
    int b = blockIdx.x >> 6, chunk = blockIdx.x & 63, tid = threadIdx.x;
    int rowslot = tid >> 4, col = tid & 15;
    const float* P = ws + OFF_P + (size_t)b * 512;
    float4 er4 = *(const float4*)(P + 256 + col * 4);
    float4 ad4 = *(const float4*)(P + 320 + col * 4);
    float isr = 1.f / ws[OFF_SGR + b];
    float isw = 1.f / ws[OFF_SGW + b];
    const float* wgr = ws + OFF_WGR + (size_t)b * SS;
    const float* wgw = ws + OFF_WGW + (size_t)b * SS;
    float* nm = out + 2048 + (size_t)b * SS * 64;
    float4 racc = {0.f, 0.f, 0.f, 0.f};
    int row0 = chunk * 256;
    for (int it = 0; it < 16; ++it) {
        int row = row0 + it * 16 + rowslot;
        float wr = wgr[row] * isr;
        float ww = wgw[row] * isw;
        float4 v = *(const float4*)(mem + ((size_t)b * SS + row) * 64 + col * 4);
        racc.x = fmaf(wr, v.x, racc.x);
        racc.y = fmaf(wr, v.y, racc.y);
        racc.z = fmaf(wr, v.z, racc.z);
        racc.w = fmaf(wr, v.w, racc.w);
        float4 o4;
        o4.x = v.x * (1.f - ww * er4.x) + ww * ad4.x;
        o4.y = v.y * (1.f - ww * er4.y) + ww * ad4.y;
        o4.z = v.z * (1.f - ww * er4.z) + ww * ad4.z;
        o4.w = v.w * (1.f - ww * er4.w) + ww * ad4.w;
        *(float4*)(nm + (size_t)row * 64 + col * 4) = o4;
    }
    __shared__ float4 red[256];
    red[tid] = racc;
    __syncthreads();
    if (tid < 16) {
        float4 a = red[tid];
        for (int rs = 1; rs < 16; ++rs) {
            float4 t2 = red[rs * 16 + tid];
            a.x += t2.x; a.y += t2.y; a.z += t2.z; a.w += t2.w;
        }
        atomicAdd(ws + OFF_R + b * 64 + tid * 4 + 0, a.x);
        atomicAdd(ws + OFF_R + b * 64 + tid * 4 + 1, a.y);
        atomicAdd(ws + OFF_R + b * 64 + tid * 4 + 2, a.z);
        atomicAdd(ws + OFF_R + b * 64 + tid * 4 + 3, a.w);
    }
}

// output = softmax(concat(h, r) @ W_o.T + b_o); one wave per batch.
__global__ void k_out(const float* __restrict__ ws, const float* __restrict__ W_o,
                      const float* __restrict__ b_o, float* __restrict__ out) {
    int b = blockIdx.x, o = threadIdx.x;  // 64 threads
    const float* h = ws + OFF_H + (size_t)b * 512;
    const float* r = ws + OFF_R + (size_t)b * 64;
    const float* w = W_o + (size_t)o * 576;
    float acc = b_o[o];
    for (int t = 0; t < 512; t++) acc = fmaf(h[t], w[t], acc);
    for (int m = 0; m < 64; m++) acc = fmaf(r[m], w[512 + m], acc);
    float mx = acc;
    #pragma unroll
    for (int off = 32; off >= 1; off >>= 1) mx = fmaxf(mx, __shfl_xor(mx, off));
    float e = expf(acc - mx);
    float sm = e;
    #pragma unroll
    for (int off = 32; off >= 1; off >>= 1) sm += __shfl_xor(sm, off);
    out[b * 64 + o] = e / sm;
}

extern "C" void kernel_launch(void* const* d_in, const int* in_sizes, int n_in,
                              void* d_out, int out_size, void* d_ws, size_t ws_size,
                              hipStream_t stream) {
    const float* x    = (const float*)d_in[0];
    const float* pdo  = (const float*)d_in[1];
    const float* prv  = (const float*)d_in[2];
    const float* mem  = (const float*)d_in[3];
    const float* W_ih = (const float*)d_in[4];
    // d_in[5] = W_hh (unused by reference math)
    const float* b_ih = (const float*)d_in[6];
    const float* b_hh = (const float*)d_in[7];
    const float* W_r  = (const float*)d_in[8];
    const float* b_r  = (const float*)d_in[9];
    const float* W_w  = (const float*)d_in[10];
    const float* b_w  = (const float*)d_in[11];
    const float* W_o  = (const float*)d_in[12];
    const float* b_o  = (const float*)d_in[13];
    float* out = (float*)d_out;
    float* ws  = (float*)d_ws;

    k_lstm<<<BB * 512 / 4, 256, 0, stream>>>(x, pdo, prv, W_ih, b_ih, b_hh, ws);
    k_heads<<<(BB * 268) / 4, 256, 0, stream>>>(W_r, b_r, W_w, b_w, ws);
    k_scorewgam<<<BB * 64, 256, 0, stream>>>(mem, ws);
    k_update<<<BB * 64, 256, 0, stream>>>(mem, ws, out);
    k_out<<<BB, 64, 0, stream>>>(ws, W_o, b_o, out);
}

// Round 5
// 115.531 us; speedup vs baseline: 1.7833x; 1.0521x over previous
//
#include <hip/hip_runtime.h>
#include <hip/hip_bf16.h>
#include <math.h>

// Problem constants
#define BB 32
#define SS 16384
#define MM 64
#define HID 512
#define EPSV 1e-8f

// ws layout (in floats)
#define OFF_H   0            // 32*512 h vectors
#define OFF_P   16384        // 32*512 per-batch params (sparse layout, see below)
#define OFF_SER 32768        // (unused now, still zeroed)
#define OFF_SEW 32800
#define OFF_SGR 32832        // 32 sum of wgam_r
#define OFF_SGW 32864        // 32 sum of wgam_w
#define OFF_R   32896        // 32*64 read vector accumulators
#define OFF_ER  40960        // (unused now)
#define OFF_EW  (OFF_ER + BB*SS)
#define OFF_WGR (OFF_EW + BB*SS)
#define OFF_WGW (OFF_WGR + BB*SS)
//
// P-region per-batch layout (512 floats):
//  [0..63]   k_r            [64] beta_r  [69] gamma_r   [96..98] raw shift_r
//  [128..191] k_w           [192] beta_w [197] gamma_w  [224..226] raw shift_w
//  [256..319] erase         [320..383] add

__device__ __forceinline__ float sigmoidf_(float x) { return 1.f / (1.f + expf(-x)); }
__device__ __forceinline__ float softplusf_(float x) {
    return (x > 0.f) ? x + log1pf(expf(-x)) : log1pf(expf(x));
}

// One wave per (b,t): h[b][t]. Block 0 also zeroes the atomic accumulators.
__global__ void k_lstm(const float* __restrict__ x, const float* __restrict__ pdo,
                       const float* __restrict__ prv,
                       const float* __restrict__ W_ih, const float* __restrict__ b_ih,
                       const float* __restrict__ b_hh, float* __restrict__ ws) {
    if (blockIdx.x == 0) {
        for (int i = threadIdx.x; i < 128 + BB * MM; i += 256) ws[OFF_SER + i] = 0.f;
    }
    int wid = blockIdx.x * 4 + (threadIdx.x >> 6);   // 0 .. 32*512-1
    int lane = threadIdx.x & 63;
    int b = wid >> 9, t = wid & 511;
    float x0 = x[b * 64 + lane];
    float x1 = pdo[b * 64 + lane];
    float x2 = prv[b * 64 + lane];
    const float* wi = W_ih + (size_t)t * 192;
    const float* wg = W_ih + (size_t)(1024 + t) * 192;
    const float* wo = W_ih + (size_t)(1536 + t) * 192;
    float zi = x0 * wi[lane] + x1 * wi[64 + lane] + x2 * wi[128 + lane];
    float zg = x0 * wg[lane] + x1 * wg[64 + lane] + x2 * wg[128 + lane];
    float zo = x0 * wo[lane] + x1 * wo[64 + lane] + x2 * wo[128 + lane];
    #pragma unroll
    for (int off = 32; off >= 1; off >>= 1) {
        zi += __shfl_xor(zi, off);
        zg += __shfl_xor(zg, off);
        zo += __shfl_xor(zo, off);
    }
    if (lane == 0) {
        zi += b_ih[t] + b_hh[t];
        zg += b_ih[1024 + t] + b_hh[1024 + t];
        zo += b_ih[1536 + t] + b_hh[1536 + t];
        float c = sigmoidf_(zi) * tanhf(zg);
        ws[OFF_H + (size_t)b * 512 + t] = sigmoidf_(zo) * tanhf(c);
    }
}

// One wave per (b, head-row j): j<70 read head, else write head row j-70.
__global__ void k_heads(const float* __restrict__ W_r, const float* __restrict__ b_r,
                        const float* __restrict__ W_w, const float* __restrict__ b_w,
                        float* __restrict__ ws) {
    int wid = blockIdx.x * 4 + (threadIdx.x >> 6);   // 0 .. 32*268-1
    int lane = threadIdx.x & 63;
    int b = wid / 268, j = wid % 268;
    const float* h = ws + OFF_H + (size_t)b * 512;
    const float* wrow;
    float bias;
    if (j < 70) { wrow = W_r + (size_t)j * 512; bias = b_r[j]; }
    else        { wrow = W_w + (size_t)(j - 70) * 512; bias = b_w[j - 70]; }
    float acc = 0.f;
    #pragma unroll
    for (int c = 0; c < 8; c++) acc = fmaf(h[c * 64 + lane], wrow[c * 64 + lane], acc);
    #pragma unroll
    for (int off = 32; off >= 1; off >>= 1) acc += __shfl_xor(acc, off);
    if (lane != 0) return;
    acc += bias;
    float* P = ws + OFF_P + (size_t)b * 512;
    if (j < 70) {
        if (j < 64)       P[j] = acc;                       // k_r
        else if (j == 64) P[64] = softplusf_(acc);          // beta_r
        else if (j == 65) P[65] = sigmoidf_(acc);           // g_r (cancels; unused)
        else if (j <= 68) P[96 + (j - 66)] = acc;           // raw shift_r
        else              P[69] = 1.f + softplusf_(acc);    // gamma_r
    } else {
        int jj = j - 70;
        if (jj < 64)       P[128 + jj] = acc;               // k_w
        else if (jj == 64) P[192] = softplusf_(acc);        // beta_w
        else if (jj == 65) P[193] = sigmoidf_(acc);         // g_w (cancels; unused)
        else if (jj <= 68) P[224 + (jj - 66)] = acc;        // raw shift_w
        else if (jj == 69) P[197] = 1.f + softplusf_(acc);  // gamma_w
        else if (jj < 134) P[256 + (jj - 70)] = acc;        // erase
        else               P[320 + (jj - 134)] = acc;       // add
    }
}

// Fused scores+conv+sharpen, ONE LANE PER ROW (no shuffles in main path).
// E = exp(beta*(cos-1)); wgam = (conv(s,E))^gamma; softmax denom & g cancel.
__global__ void k_scorewgam(const float* __restrict__ mem, float* __restrict__ ws) {
    int b = blockIdx.x >> 6;
    int chunk = blockIdx.x & 63;
    int tid = threadIdx.x;
    const float* P = ws + OFF_P + (size_t)b * 512;

    __shared__ float sh_kr[64], sh_kw[64];
    __shared__ float sh_er[258], sh_ew[258];
    __shared__ float par[8];   // ikr, ikw, sr0..2, sw0..2
    __shared__ float lr[4], lw[4];

    // prologue: stage keys to LDS, key norms (wave 0) + shift softmaxes (tid 0)
    if (tid < 64) {
        float kr = P[tid], kw = P[128 + tid];
        sh_kr[tid] = kr; sh_kw[tid] = kw;
        float nr = kr * kr, nw = kw * kw;
        #pragma unroll
        for (int off = 32; off >= 1; off >>= 1) {
            nr += __shfl_xor(nr, off);
            nw += __shfl_xor(nw, off);
        }
        if (tid == 0) {
            par[0] = 1.f / fmaxf(sqrtf(nr), EPSV);
            par[1] = 1.f / fmaxf(sqrtf(nw), EPSV);
            float s0 = softplusf_(P[96]), s1 = softplusf_(P[97]), s2 = softplusf_(P[98]);
            float mx = fmaxf(s0, fmaxf(s1, s2));
            float e0 = expf(s0 - mx), e1 = expf(s1 - mx), e2 = expf(s2 - mx);
            float si = 1.f / (e0 + e1 + e2);
            par[2] = e0 * si; par[3] = e1 * si; par[4] = e2 * si;
            s0 = softplusf_(P[224]); s1 = softplusf_(P[225]); s2 = softplusf_(P[226]);
            mx = fmaxf(s0, fmaxf(s1, s2));
            e0 = expf(s0 - mx); e1 = expf(s1 - mx); e2 = expf(s2 - mx);
            si = 1.f / (e0 + e1 + e2);
            par[5] = e0 * si; par[6] = e1 * si; par[7] = e2 * si;
        }
    }
    float beta_r = P[64], beta_w = P[192];
    float gamma_r = P[69], gamma_w = P[197];
    __syncthreads();
    float ikr = par[0], ikw = par[1];

    int row0 = chunk * 256;
    // main: this thread owns row row0+tid
    {
        const float4* mrow = (const float4*)(mem + ((size_t)b * SS + row0 + tid) * 64);
        float dr = 0.f, dw = 0.f, n2 = 0.f;
        #pragma unroll
        for (int k = 0; k < 16; k++) {
            float4 m4 = mrow[k];
            float4 kr4 = *(const float4*)(sh_kr + k * 4);
            float4 kw4 = *(const float4*)(sh_kw + k * 4);
            dr = fmaf(m4.x, kr4.x, fmaf(m4.y, kr4.y, fmaf(m4.z, kr4.z, fmaf(m4.w, kr4.w, dr))));
            dw = fmaf(m4.x, kw4.x, fmaf(m4.y, kw4.y, fmaf(m4.z, kw4.z, fmaf(m4.w, kw4.w, dw))));
            n2 = fmaf(m4.x, m4.x, fmaf(m4.y, m4.y, fmaf(m4.z, m4.z, fmaf(m4.w, m4.w, n2))));
        }
        float imn = 1.f / fmaxf(sqrtf(n2), EPSV);
        sh_er[1 + tid] = exp2f(1.44269504f * beta_r * (dr * ikr * imn - 1.f));
        sh_ew[1 + tid] = exp2f(1.44269504f * beta_w * (dw * ikw * imn - 1.f));
    }
    // halo rows row0-1 and row0+256: lanes 0..15 and 16..31 (16-lane split each)
    if (tid < 32) {
        int grp = tid >> 4, c = tid & 15;
        int hrow = grp ? ((row0 + 256) & (SS - 1)) : ((row0 - 1) & (SS - 1));
        float4 m4 = *(const float4*)(mem + ((size_t)b * SS + hrow) * 64 + c * 4);
        float4 kr4 = *(const float4*)(sh_kr + c * 4);
        float4 kw4 = *(const float4*)(sh_kw + c * 4);
        float dr = m4.x * kr4.x + m4.y * kr4.y + m4.z * kr4.z + m4.w * kr4.w;
        float dw = m4.x * kw4.x + m4.y * kw4.y + m4.z * kw4.z + m4.w * kw4.w;
        float n2 = m4.x * m4.x + m4.y * m4.y + m4.z * m4.z + m4.w * m4.w;
        #pragma unroll
        for (int off = 8; off >= 1; off >>= 1) {
            dr += __shfl_xor(dr, off);
            dw += __shfl_xor(dw, off);
            n2 += __shfl_xor(n2, off);
        }
        if (c == 0) {
            float imn = 1.f / fmaxf(sqrtf(n2), EPSV);
            int slot = grp ? 257 : 0;
            sh_er[slot] = exp2f(1.44269504f * beta_r * (dr * ikr * imn - 1.f));
            sh_ew[slot] = exp2f(1.44269504f * beta_w * (dw * ikw * imn - 1.f));
        }
    }
    __syncthreads();

    // conv + sharpen for row s = row0 + tid (fast pow: base > 0)
    float cvr = par[2] * sh_er[tid] + par[3] * sh_er[tid + 1] + par[4] * sh_er[tid + 2];
    float cvw = par[5] * sh_ew[tid] + par[6] * sh_ew[tid + 1] + par[7] * sh_ew[tid + 2];
    float wgr = exp2f(gamma_r * log2f(cvr));
    float wgw = exp2f(gamma_w * log2f(cvw));
    ws[OFF_WGR + (size_t)b * SS + row0 + tid] = wgr;
    ws[OFF_WGW + (size_t)b * SS + row0 + tid] = wgw;

    float rr = wgr, rw = wgw;
    #pragma unroll
    for (int off = 32; off >= 1; off >>= 1) {
        rr += __shfl_xor(rr, off);
        rw += __shfl_xor(rw, off);
    }
    int wv = tid >> 6, ln = tid & 63;
    if (ln == 0) { lr[wv] = rr; lw[wv] = rw; }
    __syncthreads();
    if (tid == 0) {
        atomicAdd(ws + OFF_SGR + b, lr[0] + lr[1] + lr[2] + lr[3]);
        atomicAdd(ws + OFF_SGW + b, lw[0] + lw[1] + lw[2] + lw[3]);
    }
}

// Final weights; r = sum_s w_r*mem; new_mem = mem*(1-w_w*e)+w_w*a.
__global__ void k_update(const float* __restrict__ mem, float* __restrict__ ws,
                         float* __restrict__ out) {
    int b = blockIdx.x >> 6, chunk = blockIdx.x & 63, tid = threadIdx.x;
    int rowslot = tid >> 4, col = tid & 15;
    const float* P = ws + OFF_P + (size_t)b * 512;
    float4 er4 = *(const float4*)(P + 256 + col * 4);
    float4 ad4 = *(const float4*)(P + 320 + col * 4);
    float isr = 1.f / ws[OFF_SGR + b];
    float isw = 1.f / ws[OFF_SGW + b];
    const float* wgr = ws + OFF_WGR + (size_t)b * SS;
    const float* wgw = ws + OFF_WGW + (size_t)b * SS;
    float* nm = out + 2048 + (size_t)b * SS * 64;
    float4 racc = {0.f, 0.f, 0.f, 0.f};
    int row0 = chunk * 256;
    for (int it = 0; it < 16; ++it) {
        int row = row0 + it * 16 + rowslot;
        float wr = wgr[row] * isr;
        float ww = wgw[row] * isw;
        float4 v = *(const float4*)(mem + ((size_t)b * SS + row) * 64 + col * 4);
        racc.x = fmaf(wr, v.x, racc.x);
        racc.y = fmaf(wr, v.y, racc.y);
        racc.z = fmaf(wr, v.z, racc.z);
        racc.w = fmaf(wr, v.w, racc.w);
        float4 o4;
        o4.x = v.x * (1.f - ww * er4.x) + ww * ad4.x;
        o4.y = v.y * (1.f - ww * er4.y) + ww * ad4.y;
        o4.z = v.z * (1.f - ww * er4.z) + ww * ad4.z;
        o4.w = v.w * (1.f - ww * er4.w) + ww * ad4.w;
        *(float4*)(nm + (size_t)row * 64 + col * 4) = o4;
    }
    __shared__ float4 red[256];
    red[tid] = racc;
    __syncthreads();
    if (tid < 16) {
        float4 a = red[tid];
        for (int rs = 1; rs < 16; ++rs) {
            float4 t2 = red[rs * 16 + tid];
            a.x += t2.x; a.y += t2.y; a.z += t2.z; a.w += t2.w;
        }
        atomicAdd(ws + OFF_R + b * 64 + tid * 4 + 0, a.x);
        atomicAdd(ws + OFF_R + b * 64 + tid * 4 + 1, a.y);
        atomicAdd(ws + OFF_R + b * 64 + tid * 4 + 2, a.z);
        atomicAdd(ws + OFF_R + b * 64 + tid * 4 + 3, a.w);
    }
}

// output = softmax(concat(h, r) @ W_o.T + b_o); one wave per batch.
__global__ void k_out(const float* __restrict__ ws, const float* __restrict__ W_o,
                      const float* __restrict__ b_o, float* __restrict__ out) {
    int b = blockIdx.x, o = threadIdx.x;  // 64 threads
    const float* h = ws + OFF_H + (size_t)b * 512;
    const float* r = ws + OFF_R + (size_t)b * 64;
    const float* w = W_o + (size_t)o * 576;
    float acc = b_o[o];
    for (int t = 0; t < 512; t++) acc = fmaf(h[t], w[t], acc);
    for (int m = 0; m < 64; m++) acc = fmaf(r[m], w[512 + m], acc);
    float mx = acc;
    #pragma unroll
    for (int off = 32; off >= 1; off >>= 1) mx = fmaxf(mx, __shfl_xor(mx, off));
    float e = expf(acc - mx);
    float sm = e;
    #pragma unroll
    for (int off = 32; off >= 1; off >>= 1) sm += __shfl_xor(sm, off);
    out[b * 64 + o] = e / sm;
}

extern "C" void kernel_launch(void* const* d_in, const int* in_sizes, int n_in,
                              void* d_out, int out_size, void* d_ws, size_t ws_size,
                              hipStream_t stream) {
    const float* x    = (const float*)d_in[0];
    const float* pdo  = (const float*)d_in[1];
    const float* prv  = (const float*)d_in[2];
    const float* mem  = (const float*)d_in[3];
    const float* W_ih = (const float*)d_in[4];
    // d_in[5] = W_hh (unused by reference math)
    const float* b_ih = (const float*)d_in[6];
    const float* b_hh = (const float*)d_in[7];
    const float* W_r  = (const float*)d_in[8];
    const float* b_r  = (const float*)d_in[9];
    const float* W_w  = (const float*)d_in[10];
    const float* b_w  = (const float*)d_in[11];
    const float* W_o  = (const float*)d_in[12];
    const float* b_o  = (const float*)d_in[13];
    float* out = (float*)d_out;
    float* ws  = (float*)d_ws;

    k_lstm<<<BB * 512 / 4, 256, 0, stream>>>(x, pdo, prv, W_ih, b_ih, b_hh, ws);
    k_heads<<<(BB * 268) / 4, 256, 0, stream>>>(W_r, b_r, W_w, b_w, ws);
    k_scorewgam<<<BB * 64, 256, 0, stream>>>(mem, ws);
    k_update<<<BB * 64, 256, 0, stream>>>(mem, ws, out);
    k_out<<<BB, 64, 0, stream>>>(ws, W_o, b_o, out);
}

// Round 6
// 114.286 us; speedup vs baseline: 1.8027x; 1.0109x over previous
//
#include <hip/hip_runtime.h>
#include <hip/hip_bf16.h>
#include <math.h>

// Problem constants
#define BB 32
#define SS 16384
#define MM 64
#define HID 512
#define EPSV 1e-8f

// ws layout (in floats)
#define OFF_H   0            // 32*512 h vectors
#define OFF_P   16384        // 32*512 per-batch params (sparse layout, see below)
#define OFF_SER 32768        // (unused now, still zeroed)
#define OFF_SEW 32800
#define OFF_SGR 32832        // 32 sum of wgam_r
#define OFF_SGW 32864        // 32 sum of wgam_w
#define OFF_R   32896        // 32*64 read vector accumulators
#define OFF_ER  40960        // (unused now)
#define OFF_EW  (OFF_ER + BB*SS)
#define OFF_WGR (OFF_EW + BB*SS)
#define OFF_WGW (OFF_WGR + BB*SS)
//
// P-region per-batch layout (512 floats):
//  [0..63]   k_r            [64] beta_r  [69] gamma_r   [96..98] raw shift_r
//  [128..191] k_w           [192] beta_w [197] gamma_w  [224..226] raw shift_w
//  [256..319] erase         [320..383] add

__device__ __forceinline__ float sigmoidf_(float x) { return 1.f / (1.f + expf(-x)); }
__device__ __forceinline__ float softplusf_(float x) {
    return (x > 0.f) ? x + log1pf(expf(-x)) : log1pf(expf(x));
}

// One wave per (b,t): h[b][t]. Block 0 also zeroes the atomic accumulators.
__global__ void k_lstm(const float* __restrict__ x, const float* __restrict__ pdo,
                       const float* __restrict__ prv,
                       const float* __restrict__ W_ih, const float* __restrict__ b_ih,
                       const float* __restrict__ b_hh, float* __restrict__ ws) {
    if (blockIdx.x == 0) {
        for (int i = threadIdx.x; i < 128 + BB * MM; i += 256) ws[OFF_SER + i] = 0.f;
    }
    int wid = blockIdx.x * 4 + (threadIdx.x >> 6);   // 0 .. 32*512-1
    int lane = threadIdx.x & 63;
    int b = wid >> 9, t = wid & 511;
    float x0 = x[b * 64 + lane];
    float x1 = pdo[b * 64 + lane];
    float x2 = prv[b * 64 + lane];
    const float* wi = W_ih + (size_t)t * 192;
    const float* wg = W_ih + (size_t)(1024 + t) * 192;
    const float* wo = W_ih + (size_t)(1536 + t) * 192;
    float zi = x0 * wi[lane] + x1 * wi[64 + lane] + x2 * wi[128 + lane];
    float zg = x0 * wg[lane] + x1 * wg[64 + lane] + x2 * wg[128 + lane];
    float zo = x0 * wo[lane] + x1 * wo[64 + lane] + x2 * wo[128 + lane];
    #pragma unroll
    for (int off = 32; off >= 1; off >>= 1) {
        zi += __shfl_xor(zi, off);
        zg += __shfl_xor(zg, off);
        zo += __shfl_xor(zo, off);
    }
    if (lane == 0) {
        zi += b_ih[t] + b_hh[t];
        zg += b_ih[1024 + t] + b_hh[1024 + t];
        zo += b_ih[1536 + t] + b_hh[1536 + t];
        float c = sigmoidf_(zi) * tanhf(zg);
        ws[OFF_H + (size_t)b * 512 + t] = sigmoidf_(zo) * tanhf(c);
    }
}

// One wave per (b, head-row j): j<70 read head, else write head row j-70.
__global__ void k_heads(const float* __restrict__ W_r, const float* __restrict__ b_r,
                        const float* __restrict__ W_w, const float* __restrict__ b_w,
                        float* __restrict__ ws) {
    int wid = blockIdx.x * 4 + (threadIdx.x >> 6);   // 0 .. 32*268-1
    int lane = threadIdx.x & 63;
    int b = wid / 268, j = wid % 268;
    const float* h = ws + OFF_H + (size_t)b * 512;
    const float* wrow;
    float bias;
    if (j < 70) { wrow = W_r + (size_t)j * 512; bias = b_r[j]; }
    else        { wrow = W_w + (size_t)(j - 70) * 512; bias = b_w[j - 70]; }
    float acc = 0.f;
    #pragma unroll
    for (int c = 0; c < 8; c++) acc = fmaf(h[c * 64 + lane], wrow[c * 64 + lane], acc);
    #pragma unroll
    for (int off = 32; off >= 1; off >>= 1) acc += __shfl_xor(acc, off);
    if (lane != 0) return;
    acc += bias;
    float* P = ws + OFF_P + (size_t)b * 512;
    if (j < 70) {
        if (j < 64)       P[j] = acc;                       // k_r
        else if (j == 64) P[64] = softplusf_(acc);          // beta_r
        else if (j == 65) P[65] = sigmoidf_(acc);           // g_r (cancels; unused)
        else if (j <= 68) P[96 + (j - 66)] = acc;           // raw shift_r
        else              P[69] = 1.f + softplusf_(acc);    // gamma_r
    } else {
        int jj = j - 70;
        if (jj < 64)       P[128 + jj] = acc;               // k_w
        else if (jj == 64) P[192] = softplusf_(acc);        // beta_w
        else if (jj == 65) P[193] = sigmoidf_(acc);         // g_w (cancels; unused)
        else if (jj <= 68) P[224 + (jj - 66)] = acc;        // raw shift_w
        else if (jj == 69) P[197] = 1.f + softplusf_(acc);  // gamma_w
        else if (jj < 134) P[256 + (jj - 70)] = acc;        // erase
        else               P[320 + (jj - 134)] = acc;       // add
    }
}

// Fused scores+conv+sharpen. Coalesced global->LDS tile staging (4 sub-tiles
// of 64 rows), then 4 threads per row compute dots from LDS (2 shuffle levels).
// E = exp(beta*(cos-1)); wgam = (conv(s,E))^gamma; softmax denom & g cancel.
#define PF4 17   // padded row stride in float4 units (16 data + 1 pad)
__global__ void k_scorewgam(const float* __restrict__ mem, float* __restrict__ ws) {
    int b = blockIdx.x >> 6;
    int chunk = blockIdx.x & 63;
    int tid = threadIdx.x;
    const float* P = ws + OFF_P + (size_t)b * 512;

    __shared__ float4 s_tile[64 * PF4];          // 17408 B
    __shared__ float sh_kr[64], sh_kw[64];
    __shared__ float sh_er[258], sh_ew[258];
    __shared__ float par[8];   // ikr, ikw, sr0..2, sw0..2
    __shared__ float lr[4], lw[4];

    // prologue: stage keys to LDS, key norms (wave 0) + shift softmaxes (tid 0)
    if (tid < 64) {
        float kr = P[tid], kw = P[128 + tid];
        sh_kr[tid] = kr; sh_kw[tid] = kw;
        float nr = kr * kr, nw = kw * kw;
        #pragma unroll
        for (int off = 32; off >= 1; off >>= 1) {
            nr += __shfl_xor(nr, off);
            nw += __shfl_xor(nw, off);
        }
        if (tid == 0) {
            par[0] = 1.f / fmaxf(sqrtf(nr), EPSV);
            par[1] = 1.f / fmaxf(sqrtf(nw), EPSV);
            float s0 = softplusf_(P[96]), s1 = softplusf_(P[97]), s2 = softplusf_(P[98]);
            float mx = fmaxf(s0, fmaxf(s1, s2));
            float e0 = expf(s0 - mx), e1 = expf(s1 - mx), e2 = expf(s2 - mx);
            float si = 1.f / (e0 + e1 + e2);
            par[2] = e0 * si; par[3] = e1 * si; par[4] = e2 * si;
            s0 = softplusf_(P[224]); s1 = softplusf_(P[225]); s2 = softplusf_(P[226]);
            mx = fmaxf(s0, fmaxf(s1, s2));
            e0 = expf(s0 - mx); e1 = expf(s1 - mx); e2 = expf(s2 - mx);
            si = 1.f / (e0 + e1 + e2);
            par[5] = e0 * si; par[6] = e1 * si; par[7] = e2 * si;
        }
    }
    float beta_r = P[64], beta_w = P[192];
    float gamma_r = P[69], gamma_w = P[197];
    __syncthreads();
    float ikr = par[0], ikw = par[1];
    int row0 = chunk * 256;

    // halo rows row0-1 and row0+256: lanes 0..15 and 16..31 (16-lane split each)
    if (tid < 32) {
        int grp = tid >> 4, c = tid & 15;
        int hrow = grp ? ((row0 + 256) & (SS - 1)) : ((row0 - 1) & (SS - 1));
        float4 m4 = *(const float4*)(mem + ((size_t)b * SS + hrow) * 64 + c * 4);
        float4 kr4 = *(const float4*)(sh_kr + c * 4);
        float4 kw4 = *(const float4*)(sh_kw + c * 4);
        float dr = m4.x * kr4.x + m4.y * kr4.y + m4.z * kr4.z + m4.w * kr4.w;
        float dw = m4.x * kw4.x + m4.y * kw4.y + m4.z * kw4.z + m4.w * kw4.w;
        float n2 = m4.x * m4.x + m4.y * m4.y + m4.z * m4.z + m4.w * m4.w;
        #pragma unroll
        for (int off = 8; off >= 1; off >>= 1) {
            dr += __shfl_xor(dr, off);
            dw += __shfl_xor(dw, off);
            n2 += __shfl_xor(n2, off);
        }
        if (c == 0) {
            float imn = 1.f / fmaxf(sqrtf(n2), EPSV);
            int slot = grp ? 257 : 0;
            sh_er[slot] = exp2f(1.44269504f * beta_r * (dr * ikr * imn - 1.f));
            sh_ew[slot] = exp2f(1.44269504f * beta_w * (dw * ikw * imn - 1.f));
        }
    }

    // main: 4 sub-tiles of 64 rows
    int rq = tid >> 2;          // row_local 0..63
    int q  = tid & 3;           // quarter of the row
    for (int t = 0; t < 4; ++t) {
        const float4* src = (const float4*)(mem + ((size_t)b * SS + row0 + t * 64) * 64);
        #pragma unroll
        for (int j = 0; j < 4; ++j) {
            int li = tid + j * 256;              // linear float4 index 0..1023
            s_tile[(li >> 4) * PF4 + (li & 15)] = src[li];
        }
        __syncthreads();
        float dr = 0.f, dw = 0.f, n2 = 0.f;
        #pragma unroll
        for (int i = 0; i < 4; ++i) {
            float4 m4 = s_tile[rq * PF4 + q * 4 + i];
            float4 kr4 = *(const float4*)(sh_kr + (q * 4 + i) * 4);
            float4 kw4 = *(const float4*)(sh_kw + (q * 4 + i) * 4);
            dr = fmaf(m4.x, kr4.x, fmaf(m4.y, kr4.y, fmaf(m4.z, kr4.z, fmaf(m4.w, kr4.w, dr))));
            dw = fmaf(m4.x, kw4.x, fmaf(m4.y, kw4.y, fmaf(m4.z, kw4.z, fmaf(m4.w, kw4.w, dw))));
            n2 = fmaf(m4.x, m4.x, fmaf(m4.y, m4.y, fmaf(m4.z, m4.z, fmaf(m4.w, m4.w, n2))));
        }
        dr += __shfl_xor(dr, 1); dr += __shfl_xor(dr, 2);
        dw += __shfl_xor(dw, 1); dw += __shfl_xor(dw, 2);
        n2 += __shfl_xor(n2, 1); n2 += __shfl_xor(n2, 2);
        if (q == 0) {
            float imn = 1.f / fmaxf(sqrtf(n2), EPSV);
            int rb = t * 64 + rq;                // row in block 0..255
            sh_er[1 + rb] = exp2f(1.44269504f * beta_r * (dr * ikr * imn - 1.f));
            sh_ew[1 + rb] = exp2f(1.44269504f * beta_w * (dw * ikw * imn - 1.f));
        }
        __syncthreads();
    }

    // conv + sharpen for row s = row0 + tid (fast pow: base > 0)
    float cvr = par[2] * sh_er[tid] + par[3] * sh_er[tid + 1] + par[4] * sh_er[tid + 2];
    float cvw = par[5] * sh_ew[tid] + par[6] * sh_ew[tid + 1] + par[7] * sh_ew[tid + 2];
    float wgr = exp2f(gamma_r * log2f(cvr));
    float wgw = exp2f(gamma_w * log2f(cvw));
    ws[OFF_WGR + (size_t)b * SS + row0 + tid] = wgr;
    ws[OFF_WGW + (size_t)b * SS + row0 + tid] = wgw;

    float rr = wgr, rw = wgw;
    #pragma unroll
    for (int off = 32; off >= 1; off >>= 1) {
        rr += __shfl_xor(rr, off);
        rw += __shfl_xor(rw, off);
    }
    int wv = tid >> 6, ln = tid & 63;
    if (ln == 0) { lr[wv] = rr; lw[wv] = rw; }
    __syncthreads();
    if (tid == 0) {
        atomicAdd(ws + OFF_SGR + b, lr[0] + lr[1] + lr[2] + lr[3]);
        atomicAdd(ws + OFF_SGW + b, lw[0] + lw[1] + lw[2] + lw[3]);
    }
}

// Final weights; r = sum_s w_r*mem; new_mem = mem*(1-w_w*e)+w_w*a.
__global__ void k_update(const float* __restrict__ mem, float* __restrict__ ws,
                         float* __restrict__ out) {
    int b = blockIdx.x >> 6, chunk = blockIdx.x & 63, tid = threadIdx.x;
    int rowslot = tid >> 4, col = tid & 15;
    const float* P = ws + OFF_P + (size_t)b * 512;
    float4 er4 = *(const float4*)(P + 256 + col * 4);
    float4 ad4 = *(const float4*)(P + 320 + col * 4);
    float isr = 1.f / ws[OFF_SGR + b];
    float isw = 1.f / ws[OFF_SGW + b];
    const float* wgr = ws + OFF_WGR + (size_t)b * SS;
    const float* wgw = ws + OFF_WGW + (size_t)b * SS;
    float* nm = out + 2048 + (size_t)b * SS * 64;
    float4 racc = {0.f, 0.f, 0.f, 0.f};
    int row0 = chunk * 256;
    for (int it = 0; it < 16; ++it) {
        int row = row0 + it * 16 + rowslot;
        float wr = wgr[row] * isr;
        float ww = wgw[row] * isw;
        float4 v = *(const float4*)(mem + ((size_t)b * SS + row) * 64 + col * 4);
        racc.x = fmaf(wr, v.x, racc.x);
        racc.y = fmaf(wr, v.y, racc.y);
        racc.z = fmaf(wr, v.z, racc.z);
        racc.w = fmaf(wr, v.w, racc.w);
        float4 o4;
        o4.x = v.x * (1.f - ww * er4.x) + ww * ad4.x;
        o4.y = v.y * (1.f - ww * er4.y) + ww * ad4.y;
        o4.z = v.z * (1.f - ww * er4.z) + ww * ad4.z;
        o4.w = v.w * (1.f - ww * er4.w) + ww * ad4.w;
        *(float4*)(nm + (size_t)row * 64 + col * 4) = o4;
    }
    __shared__ float4 red[256];
    red[tid] = racc;
    __syncthreads();
    if (tid < 16) {
        float4 a = red[tid];
        for (int rs = 1; rs < 16; ++rs) {
            float4 t2 = red[rs * 16 + tid];
            a.x += t2.x; a.y += t2.y; a.z += t2.z; a.w += t2.w;
        }
        atomicAdd(ws + OFF_R + b * 64 + tid * 4 + 0, a.x);
        atomicAdd(ws + OFF_R + b * 64 + tid * 4 + 1, a.y);
        atomicAdd(ws + OFF_R + b * 64 + tid * 4 + 2, a.z);
        atomicAdd(ws + OFF_R + b * 64 + tid * 4 + 3, a.w);
    }
}

// output = softmax(concat(h, r) @ W_o.T + b_o); one wave per batch.
__global__ void k_out(const float* __restrict__ ws, const float* __restrict__ W_o,
                      const float* __restrict__ b_o, float* __restrict__ out) {
    int b = blockIdx.x, o = threadIdx.x;  // 64 threads
    const float* h = ws + OFF_H + (size_t)b * 512;
    const float* r = ws + OFF_R + (size_t)b * 64;
    const float* w = W_o + (size_t)o * 576;
    float acc = b_o[o];
    for (int t = 0; t < 512; t++) acc = fmaf(h[t], w[t], acc);
    for (int m = 0; m < 64; m++) acc = fmaf(r[m], w[512 + m], acc);
    float mx = acc;
    #pragma unroll
    for (int off = 32; off >= 1; off >>= 1) mx = fmaxf(mx, __shfl_xor(mx, off));
    float e = expf(acc - mx);
    float sm = e;
    #pragma unroll
    for (int off = 32; off >= 1; off >>= 1) sm += __shfl_xor(sm, off);
    out[b * 64 + o] = e / sm;
}

extern "C" void kernel_launch(void* const* d_in, const int* in_sizes, int n_in,
                              void* d_out, int out_size, void* d_ws, size_t ws_size,
                              hipStream_t stream) {
    const float* x    = (const float*)d_in[0];
    const float* pdo  = (const float*)d_in[1];
    const float* prv  = (const float*)d_in[2];
    const float* mem  = (const float*)d_in[3];
    const float* W_ih = (const float*)d_in[4];
    // d_in[5] = W_hh (unused by reference math)
    const float* b_ih = (const float*)d_in[6];
    const float* b_hh = (const float*)d_in[7];
    const float* W_r  = (const float*)d_in[8];
    const float* b_r  = (const float*)d_in[9];
    const float* W_w  = (const float*)d_in[10];
    const float* b_w  = (const float*)d_in[11];
    const float* W_o  = (const float*)d_in[12];
    const float* b_o  = (const float*)d_in[13];
    float* out = (float*)d_out;
    float* ws  = (float*)d_ws;

    k_lstm<<<BB * 512 / 4, 256, 0, stream>>>(x, pdo, prv, W_ih, b_ih, b_hh, ws);
    k_heads<<<(BB * 268) / 4, 256, 0, stream>>>(W_r, b_r, W_w, b_w, ws);
    k_scorewgam<<<BB * 64, 256, 0, stream>>>(mem, ws);
    k_update<<<BB * 64, 256, 0, stream>>>(mem, ws, out);
    k_out<<<BB, 64, 0, stream>>>(ws, W_o, b_o, out);
}

// Round 7
// 97.012 us; speedup vs baseline: 2.1237x; 1.1781x over previous
//
#include <hip/hip_runtime.h>
#include <hip/hip_bf16.h>
#include <math.h>

// Problem constants
#define BB 32
#define SS 16384
#define MM 64
#define HID 512
#define EPSV 1e-8f

// ws layout (in floats)
#define OFF_H    0                 // 32*512 h vectors
#define OFF_P    16384             // 32*512 per-batch params (sparse, see below)
#define OFF_SGRP 32768             // 32*64 per-chunk wgam_r partial sums
#define OFF_SGWP (OFF_SGRP + BB*64)
#define OFF_RP   (OFF_SGWP + BB*64)       // 32*64*64 per-chunk r partials
#define OFF_WGR  (OFF_RP + BB*64*64)      // 32*16384
#define OFF_WGW  (OFF_WGR + BB*SS)        // 32*16384; total ~4.9 MB
//
// P-region per-batch layout (512 floats):
//  [0..63]   k_r            [64] beta_r  [69] gamma_r   [96..98] raw shift_r
//  [128..191] k_w           [192] beta_w [197] gamma_w  [224..226] raw shift_w
//  [256..319] erase         [320..383] add

__device__ __forceinline__ float sigmoidf_(float x) { return 1.f / (1.f + expf(-x)); }
__device__ __forceinline__ float softplusf_(float x) {
    return (x > 0.f) ? x + log1pf(expf(-x)) : log1pf(expf(x));
}

// One wave per (b,t): h[b][t].
__global__ void k_lstm(const float* __restrict__ x, const float* __restrict__ pdo,
                       const float* __restrict__ prv,
                       const float* __restrict__ W_ih, const float* __restrict__ b_ih,
                       const float* __restrict__ b_hh, float* __restrict__ ws) {
    int wid = blockIdx.x * 4 + (threadIdx.x >> 6);   // 0 .. 32*512-1
    int lane = threadIdx.x & 63;
    int b = wid >> 9, t = wid & 511;
    float x0 = x[b * 64 + lane];
    float x1 = pdo[b * 64 + lane];
    float x2 = prv[b * 64 + lane];
    const float* wi = W_ih + (size_t)t * 192;
    const float* wg = W_ih + (size_t)(1024 + t) * 192;
    const float* wo = W_ih + (size_t)(1536 + t) * 192;
    float zi = x0 * wi[lane] + x1 * wi[64 + lane] + x2 * wi[128 + lane];
    float zg = x0 * wg[lane] + x1 * wg[64 + lane] + x2 * wg[128 + lane];
    float zo = x0 * wo[lane] + x1 * wo[64 + lane] + x2 * wo[128 + lane];
    #pragma unroll
    for (int off = 32; off >= 1; off >>= 1) {
        zi += __shfl_xor(zi, off);
        zg += __shfl_xor(zg, off);
        zo += __shfl_xor(zo, off);
    }
    if (lane == 0) {
        zi += b_ih[t] + b_hh[t];
        zg += b_ih[1024 + t] + b_hh[1024 + t];
        zo += b_ih[1536 + t] + b_hh[1536 + t];
        float c = sigmoidf_(zi) * tanhf(zg);
        ws[OFF_H + (size_t)b * 512 + t] = sigmoidf_(zo) * tanhf(c);
    }
}

// One wave per (b, head-row j): j<70 read head, else write head row j-70.
__global__ void k_heads(const float* __restrict__ W_r, const float* __restrict__ b_r,
                        const float* __restrict__ W_w, const float* __restrict__ b_w,
                        float* __restrict__ ws) {
    int wid = blockIdx.x * 4 + (threadIdx.x >> 6);   // 0 .. 32*268-1
    int lane = threadIdx.x & 63;
    int b = wid / 268, j = wid % 268;
    const float* h = ws + OFF_H + (size_t)b * 512;
    const float* wrow;
    float bias;
    if (j < 70) { wrow = W_r + (size_t)j * 512; bias = b_r[j]; }
    else        { wrow = W_w + (size_t)(j - 70) * 512; bias = b_w[j - 70]; }
    float acc = 0.f;
    #pragma unroll
    for (int c = 0; c < 8; c++) acc = fmaf(h[c * 64 + lane], wrow[c * 64 + lane], acc);
    #pragma unroll
    for (int off = 32; off >= 1; off >>= 1) acc += __shfl_xor(acc, off);
    if (lane != 0) return;
    acc += bias;
    float* P = ws + OFF_P + (size_t)b * 512;
    if (j < 70) {
        if (j < 64)       P[j] = acc;                       // k_r
        else if (j == 64) P[64] = softplusf_(acc);          // beta_r
        else if (j == 65) P[65] = sigmoidf_(acc);           // g_r (cancels; unused)
        else if (j <= 68) P[96 + (j - 66)] = acc;           // raw shift_r
        else              P[69] = 1.f + softplusf_(acc);    // gamma_r
    } else {
        int jj = j - 70;
        if (jj < 64)       P[128 + jj] = acc;               // k_w
        else if (jj == 64) P[192] = softplusf_(acc);        // beta_w
        else if (jj == 65) P[193] = sigmoidf_(acc);         // g_w (cancels; unused)
        else if (jj <= 68) P[224 + (jj - 66)] = acc;        // raw shift_w
        else if (jj == 69) P[197] = 1.f + softplusf_(acc);  // gamma_w
        else if (jj < 134) P[256 + (jj - 70)] = acc;        // erase
        else               P[320 + (jj - 134)] = acc;       // add
    }
}

// Fused scores+conv+sharpen. 4 lanes per row, register-resident, ZERO barriers
// in the main loop (only one before the conv tail). Per-chunk sums, no atomics.
// E = exp(beta*(cos-1)); wgam = (conv(s,E))^gamma; softmax denom & g cancel.
__global__ void k_scorewgam(const float* __restrict__ mem, float* __restrict__ ws) {
    int b = blockIdx.x >> 6;
    int chunk = blockIdx.x & 63;
    int tid = threadIdx.x;
    const float* P = ws + OFF_P + (size_t)b * 512;

    __shared__ float sh_kr[64], sh_kw[64];
    __shared__ float sh_er[258], sh_ew[258];
    __shared__ float par[8];   // ikr, ikw, sr0..2, sw0..2
    __shared__ float lr[4], lw[4];

    // prologue: stage keys to LDS, key norms (wave 0) + shift softmaxes (tid 0)
    if (tid < 64) {
        float kr = P[tid], kw = P[128 + tid];
        sh_kr[tid] = kr; sh_kw[tid] = kw;
        float nr = kr * kr, nw = kw * kw;
        #pragma unroll
        for (int off = 32; off >= 1; off >>= 1) {
            nr += __shfl_xor(nr, off);
            nw += __shfl_xor(nw, off);
        }
        if (tid == 0) {
            par[0] = 1.f / fmaxf(sqrtf(nr), EPSV);
            par[1] = 1.f / fmaxf(sqrtf(nw), EPSV);
            float s0 = softplusf_(P[96]), s1 = softplusf_(P[97]), s2 = softplusf_(P[98]);
            float mx = fmaxf(s0, fmaxf(s1, s2));
            float e0 = expf(s0 - mx), e1 = expf(s1 - mx), e2 = expf(s2 - mx);
            float si = 1.f / (e0 + e1 + e2);
            par[2] = e0 * si; par[3] = e1 * si; par[4] = e2 * si;
            s0 = softplusf_(P[224]); s1 = softplusf_(P[225]); s2 = softplusf_(P[226]);
            mx = fmaxf(s0, fmaxf(s1, s2));
            e0 = expf(s0 - mx); e1 = expf(s1 - mx); e2 = expf(s2 - mx);
            si = 1.f / (e0 + e1 + e2);
            par[5] = e0 * si; par[6] = e1 * si; par[7] = e2 * si;
        }
    }
    float beta_r = P[64], beta_w = P[192];
    float gamma_r = P[69], gamma_w = P[197];
    __syncthreads();
    float ikr = par[0], ikw = par[1];
    int row0 = chunk * 256;

    // halo rows row0-1 and row0+256: lanes 0..15 and 16..31 (16-lane split each)
    if (tid < 32) {
        int grp = tid >> 4, c = tid & 15;
        int hrow = grp ? ((row0 + 256) & (SS - 1)) : ((row0 - 1) & (SS - 1));
        float4 m4 = *(const float4*)(mem + ((size_t)b * SS + hrow) * 64 + c * 4);
        float4 kr4 = *(const float4*)(sh_kr + c * 4);
        float4 kw4 = *(const float4*)(sh_kw + c * 4);
        float dr = m4.x * kr4.x + m4.y * kr4.y + m4.z * kr4.z + m4.w * kr4.w;
        float dw = m4.x * kw4.x + m4.y * kw4.y + m4.z * kw4.z + m4.w * kw4.w;
        float n2 = m4.x * m4.x + m4.y * m4.y + m4.z * m4.z + m4.w * m4.w;
        #pragma unroll
        for (int off = 8; off >= 1; off >>= 1) {
            dr += __shfl_xor(dr, off);
            dw += __shfl_xor(dw, off);
            n2 += __shfl_xor(n2, off);
        }
        if (c == 0) {
            float imn = 1.f / fmaxf(sqrtf(n2), EPSV);
            int slot = grp ? 257 : 0;
            sh_er[slot] = exp2f(1.44269504f * beta_r * (dr * ikr * imn - 1.f));
            sh_ew[slot] = exp2f(1.44269504f * beta_w * (dw * ikw * imn - 1.f));
        }
    }

    // main: wave w owns rows [w*64, w*64+64); per iter 64 lanes = 16 rows x 4 quarters
    int w = tid >> 6, lane = tid & 63;
    int rw = lane >> 2, q = lane & 3;
    float4 kr0 = *(const float4*)(sh_kr + q * 16);
    float4 kr1 = *(const float4*)(sh_kr + q * 16 + 4);
    float4 kr2 = *(const float4*)(sh_kr + q * 16 + 8);
    float4 kr3 = *(const float4*)(sh_kr + q * 16 + 12);
    float4 kw0 = *(const float4*)(sh_kw + q * 16);
    float4 kw1 = *(const float4*)(sh_kw + q * 16 + 4);
    float4 kw2 = *(const float4*)(sh_kw + q * 16 + 8);
    float4 kw3 = *(const float4*)(sh_kw + q * 16 + 12);
    #pragma unroll 2
    for (int it = 0; it < 4; ++it) {
        int r = w * 64 + it * 16 + rw;           // 0..255 within chunk
        const float4* rp = (const float4*)(mem + ((size_t)b * SS + row0 + r) * 64) + q * 4;
        float4 a0 = rp[0], a1 = rp[1], a2 = rp[2], a3 = rp[3];
        float dr, dw, n2;
        dr = a0.x*kr0.x + a0.y*kr0.y + a0.z*kr0.z + a0.w*kr0.w;
        dr = fmaf(a1.x,kr1.x, fmaf(a1.y,kr1.y, fmaf(a1.z,kr1.z, fmaf(a1.w,kr1.w, dr))));
        dr = fmaf(a2.x,kr2.x, fmaf(a2.y,kr2.y, fmaf(a2.z,kr2.z, fmaf(a2.w,kr2.w, dr))));
        dr = fmaf(a3.x,kr3.x, fmaf(a3.y,kr3.y, fmaf(a3.z,kr3.z, fmaf(a3.w,kr3.w, dr))));
        dw = a0.x*kw0.x + a0.y*kw0.y + a0.z*kw0.z + a0.w*kw0.w;
        dw = fmaf(a1.x,kw1.x, fmaf(a1.y,kw1.y, fmaf(a1.z,kw1.z, fmaf(a1.w,kw1.w, dw))));
        dw = fmaf(a2.x,kw2.x, fmaf(a2.y,kw2.y, fmaf(a2.z,kw2.z, fmaf(a2.w,kw2.w, dw))));
        dw = fmaf(a3.x,kw3.x, fmaf(a3.y,kw3.y, fmaf(a3.z,kw3.z, fmaf(a3.w,kw3.w, dw))));
        n2 = a0.x*a0.x + a0.y*a0.y + a0.z*a0.z + a0.w*a0.w;
        n2 = fmaf(a1.x,a1.x, fmaf(a1.y,a1.y, fmaf(a1.z,a1.z, fmaf(a1.w,a1.w, n2))));
        n2 = fmaf(a2.x,a2.x, fmaf(a2.y,a2.y, fmaf(a2.z,a2.z, fmaf(a2.w,a2.w, n2))));
        n2 = fmaf(a3.x,a3.x, fmaf(a3.y,a3.y, fmaf(a3.z,a3.z, fmaf(a3.w,a3.w, n2))));
        dr += __shfl_xor(dr, 1); dr += __shfl_xor(dr, 2);
        dw += __shfl_xor(dw, 1); dw += __shfl_xor(dw, 2);
        n2 += __shfl_xor(n2, 1); n2 += __shfl_xor(n2, 2);
        if (q == 0) {
            float imn = 1.f / fmaxf(sqrtf(n2), EPSV);
            sh_er[1 + r] = exp2f(1.44269504f * beta_r * (dr * ikr * imn - 1.f));
            sh_ew[1 + r] = exp2f(1.44269504f * beta_w * (dw * ikw * imn - 1.f));
        }
    }
    __syncthreads();

    // conv + sharpen for row s = row0 + tid (fast pow: base > 0)
    float cvr = par[2] * sh_er[tid] + par[3] * sh_er[tid + 1] + par[4] * sh_er[tid + 2];
    float cvw = par[5] * sh_ew[tid] + par[6] * sh_ew[tid + 1] + par[7] * sh_ew[tid + 2];
    float wgr = exp2f(gamma_r * log2f(cvr));
    float wgw = exp2f(gamma_w * log2f(cvw));
    ws[OFF_WGR + (size_t)b * SS + row0 + tid] = wgr;
    ws[OFF_WGW + (size_t)b * SS + row0 + tid] = wgw;

    float rr = wgr, rw2 = wgw;
    #pragma unroll
    for (int off = 32; off >= 1; off >>= 1) {
        rr += __shfl_xor(rr, off);
        rw2 += __shfl_xor(rw2, off);
    }
    if (lane == 0) { lr[w] = rr; lw[w] = rw2; }
    __syncthreads();
    if (tid == 0) {
        ws[OFF_SGRP + b * 64 + chunk] = lr[0] + lr[1] + lr[2] + lr[3];
        ws[OFF_SGWP + b * 64 + chunk] = lw[0] + lw[1] + lw[2] + lw[3];
    }
}

// Final weights; r partials; new_mem = mem*(1-w_w*e)+w_w*a.
__global__ void k_update(const float* __restrict__ mem, float* __restrict__ ws,
                         float* __restrict__ out) {
    int b = blockIdx.x >> 6, chunk = blockIdx.x & 63, tid = threadIdx.x;
    int rowslot = tid >> 4, col = tid & 15;
    const float* P = ws + OFF_P + (size_t)b * 512;
    float4 er4 = *(const float4*)(P + 256 + col * 4);
    float4 ad4 = *(const float4*)(P + 320 + col * 4);

    // reduce per-chunk wgam sums -> 1/sum
    __shared__ float sinv[2];
    if (tid < 64) {
        float v = ws[OFF_SGRP + b * 64 + tid];
        #pragma unroll
        for (int off = 32; off >= 1; off >>= 1) v += __shfl_xor(v, off);
        if (tid == 0) sinv[0] = 1.f / v;
    } else if (tid < 128) {
        float v = ws[OFF_SGWP + b * 64 + (tid - 64)];
        #pragma unroll
        for (int off = 32; off >= 1; off >>= 1) v += __shfl_xor(v, off);
        if (tid == 64) sinv[1] = 1.f / v;
    }
    __syncthreads();
    float isr = sinv[0], isw = sinv[1];

    const float* wgr = ws + OFF_WGR + (size_t)b * SS;
    const float* wgw = ws + OFF_WGW + (size_t)b * SS;
    float* nm = out + 2048 + (size_t)b * SS * 64;
    float4 racc = {0.f, 0.f, 0.f, 0.f};
    int row0 = chunk * 256;
    for (int it = 0; it < 16; ++it) {
        int row = row0 + it * 16 + rowslot;
        float wr = wgr[row] * isr;
        float ww = wgw[row] * isw;
        float4 v = *(const float4*)(mem + ((size_t)b * SS + row) * 64 + col * 4);
        racc.x = fmaf(wr, v.x, racc.x);
        racc.y = fmaf(wr, v.y, racc.y);
        racc.z = fmaf(wr, v.z, racc.z);
        racc.w = fmaf(wr, v.w, racc.w);
        float4 o4;
        o4.x = v.x * (1.f - ww * er4.x) + ww * ad4.x;
        o4.y = v.y * (1.f - ww * er4.y) + ww * ad4.y;
        o4.z = v.z * (1.f - ww * er4.z) + ww * ad4.z;
        o4.w = v.w * (1.f - ww * er4.w) + ww * ad4.w;
        *(float4*)(nm + (size_t)row * 64 + col * 4) = o4;
    }
    __shared__ float4 red[256];
    red[tid] = racc;
    __syncthreads();
    if (tid < 16) {
        float4 a = red[tid];
        for (int rs = 1; rs < 16; ++rs) {
            float4 t2 = red[rs * 16 + tid];
            a.x += t2.x; a.y += t2.y; a.z += t2.z; a.w += t2.w;
        }
        float* rp = ws + OFF_RP + ((size_t)b * 64 + chunk) * 64;
        rp[tid * 4 + 0] = a.x;
        rp[tid * 4 + 1] = a.y;
        rp[tid * 4 + 2] = a.z;
        rp[tid * 4 + 3] = a.w;
    }
}

// output = softmax(concat(h, r) @ W_o.T + b_o); one wave per batch.
__global__ void k_out(const float* __restrict__ ws, const float* __restrict__ W_o,
                      const float* __restrict__ b_o, float* __restrict__ out) {
    int b = blockIdx.x, o = threadIdx.x;  // 64 threads
    __shared__ float sh_r[64];
    float accr = 0.f;
    for (int c = 0; c < 64; ++c) accr += ws[OFF_RP + ((size_t)b * 64 + c) * 64 + o];
    sh_r[o] = accr;
    __syncthreads();
    const float* h = ws + OFF_H + (size_t)b * 512;
    const float* w = W_o + (size_t)o * 576;
    float acc = b_o[o];
    for (int t = 0; t < 512; t++) acc = fmaf(h[t], w[t], acc);
    for (int m = 0; m < 64; m++) acc = fmaf(sh_r[m], w[512 + m], acc);
    float mx = acc;
    #pragma unroll
    for (int off = 32; off >= 1; off >>= 1) mx = fmaxf(mx, __shfl_xor(mx, off));
    float e = expf(acc - mx);
    float sm = e;
    #pragma unroll
    for (int off = 32; off >= 1; off >>= 1) sm += __shfl_xor(sm, off);
    out[b * 64 + o] = e / sm;
}

extern "C" void kernel_launch(void* const* d_in, const int* in_sizes, int n_in,
                              void* d_out, int out_size, void* d_ws, size_t ws_size,
                              hipStream_t stream) {
    const float* x    = (const float*)d_in[0];
    const float* pdo  = (const float*)d_in[1];
    const float* prv  = (const float*)d_in[2];
    const float* mem  = (const float*)d_in[3];
    const float* W_ih = (const float*)d_in[4];
    // d_in[5] = W_hh (unused by reference math)
    const float* b_ih = (const float*)d_in[6];
    const float* b_hh = (const float*)d_in[7];
    const float* W_r  = (const float*)d_in[8];
    const float* b_r  = (const float*)d_in[9];
    const float* W_w  = (const float*)d_in[10];
    const float* b_w  = (const float*)d_in[11];
    const float* W_o  = (const float*)d_in[12];
    const float* b_o  = (const float*)d_in[13];
    float* out = (float*)d_out;
    float* ws  = (float*)d_ws;

    k_lstm<<<BB * 512 / 4, 256, 0, stream>>>(x, pdo, prv, W_ih, b_ih, b_hh, ws);
    k_heads<<<(BB * 268) / 4, 256, 0, stream>>>(W_r, b_r, W_w, b_w, ws);
    k_scorewgam<<<BB * 64, 256, 0, stream>>>(mem, ws);
    k_update<<<BB * 64, 256, 0, stream>>>(mem, ws, out);
    k_out<<<BB, 64, 0, stream>>>(ws, W_o, b_o, out);
}